// Round 4
// baseline (225.166 us; speedup 1.0000x reference)
//
#include <hip/hip_runtime.h>
#include <hip/hip_bf16.h>
#include <math.h>

#define BB 4
#define TT 1024
#define FF 1024
#define DIM 1024
#define NH 16
#define HD 64
#define MROWS (BB * TT)   // 4096
#define FB (FF / 64)      // 16 uint64 mask words per row

typedef __attribute__((ext_vector_type(8))) short short8;
typedef __attribute__((ext_vector_type(4))) short short4v;
typedef __attribute__((ext_vector_type(4))) float f32x4;
typedef __hip_bfloat16 bf16;

__device__ __forceinline__ void async_copy16(const void* g, void* l) {
    __builtin_amdgcn_global_load_lds((const __attribute__((address_space(1))) void*)g,
                                     (__attribute__((address_space(3))) void*)l,
                                     16, 0, 0);
}

// ---------------------------------------------------------------------------
// Fused f32->bf16 convert (segments 0..5) + mask bit-pack (tail blocks).
// ---------------------------------------------------------------------------
struct ConvArgs {
    const float* src[6];
    bf16* dst[6];
    int nvec[6];
    int blk_end[6];
    const int* mask;
    unsigned long long* Mb;
};

__global__ __launch_bounds__(256) void convert_pack(ConvArgs a) {
    int bx = blockIdx.x;
    if (bx >= a.blk_end[5]) {
        const int lane = threadIdx.x & 63;
        const int waveId = (bx - a.blk_end[5]) * 4 + (threadIdx.x >> 6);
#pragma unroll
        for (int it = 0; it < 16; ++it) {
            int c = waveId * 16 + it;
            int v = a.mask[(size_t)c * 64 + lane];
            unsigned long long bits = __ballot(v != 0);
            if (lane == 0) a.Mb[c] = bits;
        }
        return;
    }
    int seg = 0;
#pragma unroll
    for (int k = 0; k < 5; ++k) if (bx >= a.blk_end[k]) seg = k + 1;
    int b0 = seg ? a.blk_end[seg - 1] : 0;
    int idx = (bx - b0) * 256 + threadIdx.x;
    if (idx >= a.nvec[seg]) return;
    float4 v = ((const float4*)a.src[seg])[idx];
    union { bf16 t[4]; ushort4 u; } o;
    o.t[0] = __float2bfloat16(v.x);
    o.t[1] = __float2bfloat16(v.y);
    o.t[2] = __float2bfloat16(v.z);
    o.t[3] = __float2bfloat16(v.w);
    *(ushort4*)(a.dst[seg] + 4 * (size_t)idx) = o.u;
}

// ---------------------------------------------------------------------------
// Fused Q/K/Vt projection GEMMs — 256x256 tile, 8-wave, 4-quadrant-phase
// schedule with counted vmcnt. No sched_barrier(0) in the main loop (m141:
// order-pinning costs ~40%). Builtin s_barrier; bare counted vmcnt asm.
// NEW: per-op output scale (Q pre-scaled by 0.125 = 2^-3, exact in bf16)
// so the attention softmax skips its per-element scale multiply.
// ---------------------------------------------------------------------------
#define BK 64

struct QkvArgs {
    const bf16* A[3]; const bf16* W[3]; const float* bias[3]; bf16* C[3];
    int N[3]; int biasRow[3]; float scale[3];
};

#define BARRIER() __builtin_amdgcn_s_barrier()

__global__ __launch_bounds__(512) void gemm_qkv(QkvArgs q) {
    __shared__ bf16 lds[67584];   // 132KB: 2x64KB dbuf, epilogue 256x264

    const int op = blockIdx.y;
    const bf16* A = q.A[op];
    const bf16* W = q.W[op];
    const float* bias = q.bias[op];
    bf16* C = q.C[op];
    const int N = q.N[op];
    const int brow = q.biasRow[op];
    const float sc = q.scale[op];

    // XCD-compact tile map: 8 tiles per XCD cover a 2x4 (or 4x2) region.
    const int lin = blockIdx.x;
    const int xcd = lin & 7;
    const int t8  = lin >> 3;
    int mt, nt;
    if (brow) { mt = t8 & 3; nt = xcd * 2 + (t8 >> 2); }   // op2: 4M x 16N
    else      { mt = xcd * 2 + (t8 >> 2); nt = t8 & 3; }    // op0/1: 16M x 4N
    const int m0 = mt * 256, n0 = nt * 256;

    const int tid  = threadIdx.x;
    const int lane = tid & 63;
    const int wave = tid >> 6;
    const int quad = lane >> 4;
    const int l16  = lane & 15;
    const int wm   = wave >> 2;   // 0..1 -> 64-row slice within each A-half
    const int wn   = wave & 3;    // 0..3 -> 32-col slice within each B-half
    const int wbase = tid & ~63;

    // staging: thread covers row (tid>>3), swizzled 8-elem K-group
    const int srow = tid >> 3;
    const int scol = (tid & 7) ^ (srow & 7);
    const bf16* pA = A + (size_t)(m0 + srow) * DIM + scol * 8;
    const bf16* pB = W + (size_t)(n0 + srow) * DIM + scol * 8;

#define STAGE(P, ISB, TTL, HH) do { \
    const bf16* s_ = (P) + (size_t)(HH) * (128 * DIM) + (TTL) * 64; \
    bf16* d_ = lds + ((TTL) & 1) * 32768 + (ISB) * 16384 + (HH) * 8192 + wbase * 8; \
    async_copy16(s_, d_); \
    async_copy16(s_ + 64 * DIM, d_ + 4096); \
} while (0)

    f32x4 acc[8][4] = {};
    short8 a[4][2], b[4][2];

    // prologue: tile0 all 4 halves + tile1 h0 halves; leave tile1's 4 loads
    // in flight (matches steady-state invariant).
    STAGE(pA, 0, 0, 0); STAGE(pB, 1, 0, 0);
    STAGE(pA, 0, 0, 1); STAGE(pB, 1, 0, 1);
    STAGE(pA, 0, 1, 0); STAGE(pB, 1, 1, 0);
    asm volatile("s_waitcnt vmcnt(4)");
    BARRIER();

#define LDA(AH) do { \
    _Pragma("unroll") for (int miq = 0; miq < 4; ++miq) { \
        int r_ = (AH) * 128 + wm * 64 + miq * 16 + l16; \
        const bf16* ba_ = Ab + r_ * 64; \
        a[miq][0] = *(const short8*)(ba_ + ((quad ^ (r_ & 7)) * 8)); \
        a[miq][1] = *(const short8*)(ba_ + (((quad + 4) ^ (r_ & 7)) * 8)); \
    } } while (0)

#define LDB(BH) do { \
    _Pragma("unroll") for (int niq = 0; niq < 2; ++niq) { \
        int r_ = (BH) * 128 + wn * 32 + niq * 16 + l16; \
        const bf16* bb_ = Bb + r_ * 64; \
        b[(BH) * 2 + niq][0] = *(const short8*)(bb_ + ((quad ^ (r_ & 7)) * 8)); \
        b[(BH) * 2 + niq][1] = *(const short8*)(bb_ + (((quad + 4) ^ (r_ & 7)) * 8)); \
    } } while (0)

#define MMA(AH, BH) do { \
    _Pragma("unroll") for (int miq = 0; miq < 4; ++miq) \
    _Pragma("unroll") for (int niq = 0; niq < 2; ++niq) { \
        f32x4& c_ = acc[(AH) * 4 + miq][(BH) * 2 + niq]; \
        c_ = __builtin_amdgcn_mfma_f32_16x16x32_bf16(a[miq][0], b[(BH) * 2 + niq][0], c_, 0, 0, 0); \
        c_ = __builtin_amdgcn_mfma_f32_16x16x32_bf16(a[miq][1], b[(BH) * 2 + niq][1], c_, 0, 0, 0); \
    } } while (0)

#define PHASE_MFMA(AH, BH) do { \
    BARRIER(); \
    __builtin_amdgcn_s_setprio(1); \
    MMA(AH, BH); \
    __builtin_amdgcn_s_setprio(0); \
} while (0)

#pragma unroll 2
    for (int t = 0; t < 16; ++t) {
        const bf16* Ab = lds + (t & 1) * 32768;
        const bf16* Bb = Ab + 16384;

        // q0: quadrant (A-h0, B-h0); 12 ds_reads
        LDA(0); LDB(0);
        if (t + 1 < 16) STAGE(pA, 0, t + 1, 1);
        PHASE_MFMA(0, 0);
        BARRIER();

        // q1: quadrant (A-h0, B-h1); 4 ds_reads (b[2..3] held for q3)
        LDB(1);
        if (t + 1 < 16) STAGE(pB, 1, t + 1, 1);
        PHASE_MFMA(0, 1);
        BARRIER();

        // q2: quadrant (A-h1, B-h0); 8 ds_reads. A-h0 reads fully done ->
        // safe to overwrite current buffer's A-h0 region with tile t+2.
        LDA(1);
        if (t + 2 < 16) STAGE(pA, 0, t + 2, 0);
        PHASE_MFMA(1, 0);
        BARRIER();

        // q3: quadrant (A-h1, B-h1); 0 ds_reads; counted vmcnt once/tile
        if (t + 2 < 16) STAGE(pB, 1, t + 2, 0);
        PHASE_MFMA(1, 1);
        if (t < 14)       { asm volatile("s_waitcnt vmcnt(4)"); }
        else if (t == 14) { asm volatile("s_waitcnt vmcnt(0)"); }
        BARRIER();
    }

    // epilogue: bias + scale + bf16 convert into LDS, coalesced 16B stores
    bf16* Cs = lds;
#pragma unroll
    for (int ni = 0; ni < 4; ++ni) {
        const int nl = (ni >> 1) * 128 + wn * 32 + (ni & 1) * 16 + l16;
        float bcol = brow ? 0.0f : bias[n0 + nl];
#pragma unroll
        for (int mi = 0; mi < 8; ++mi)
#pragma unroll
            for (int i = 0; i < 4; ++i) {
                const int ml = (mi >> 2) * 128 + wm * 64 + (mi & 3) * 16 + quad * 4 + i;
                float v = (acc[mi][ni][i] + (brow ? bias[m0 + ml] : bcol)) * sc;
                Cs[ml * 264 + nl] = __float2bfloat16(v);
            }
    }
    __syncthreads();
#pragma unroll
    for (int j = 0; j < 16; ++j) {
        int slot = j * 512 + tid;
        int rr = slot >> 5, cc = slot & 31;
        short8 v = *(const short8*)(Cs + rr * 264 + cc * 8);
        *(short8*)(C + (size_t)(m0 + rr) * N + n0 + cc * 8) = v;
    }
#undef STAGE
#undef LDA
#undef LDB
#undef MMA
#undef PHASE_MFMA
}

// ---------------------------------------------------------------------------
// O-projection GEMM (unchanged).
// ---------------------------------------------------------------------------
__global__ __launch_bounds__(256) void gemm_o(
    const bf16* __restrict__ A, const bf16* __restrict__ W,
    const float* __restrict__ bias, float* __restrict__ C)
{
    __shared__ float smemf[128 * 66];
    bf16* As = (bf16*)smemf;
    bf16* Bs = As + 128 * BK;

    const int lin = blockIdx.x + 16 * blockIdx.y;
    const int xcd = lin & 7;
    const int t   = lin >> 3;
    const int m0 = (xcd * 4 + (t >> 4)) * 128;
    const int n0 = (((t & 15) + 2 * xcd) & 15) * 64;

    const int tid  = threadIdx.x;
    const int lane = tid & 63;
    const int wave = tid >> 6;
    const int quad = lane >> 4;
    const int l16  = lane & 15;
    const int wm = wave & 1;
    const int wn = wave >> 1;
    const int wbase = tid & ~63;

    f32x4 acc[4][2] = {};

    for (int k0 = 0; k0 < DIM; k0 += BK) {
#pragma unroll
        for (int j = 0; j < 4; ++j) {
            int slot = j * 256 + tid;
            int r = slot >> 3;
            int g = (slot & 7) ^ (r & 7);
            async_copy16(A + (size_t)(m0 + r) * DIM + k0 + g * 8,
                         As + (size_t)(j * 256 + wbase) * 8);
        }
#pragma unroll
        for (int j = 0; j < 2; ++j) {
            int slot = j * 256 + tid;
            int r = slot >> 3;
            int g = (slot & 7) ^ (r & 7);
            async_copy16(W + (size_t)(n0 + r) * DIM + k0 + g * 8,
                         Bs + (size_t)(j * 256 + wbase) * 8);
        }
        __syncthreads();

#pragma unroll
        for (int kk = 0; kk < 2; ++kk) {
            short8 a[4], b[2];
#pragma unroll
            for (int mi = 0; mi < 4; ++mi) {
                int r = wm * 64 + mi * 16 + l16;
                int p = (kk * 4 + quad) ^ (r & 7);
                a[mi] = *(const short8*)(As + r * BK + p * 8);
            }
#pragma unroll
            for (int ni = 0; ni < 2; ++ni) {
                int r = wn * 32 + ni * 16 + l16;
                int p = (kk * 4 + quad) ^ (r & 7);
                b[ni] = *(const short8*)(Bs + r * BK + p * 8);
            }
#pragma unroll
            for (int mi = 0; mi < 4; ++mi)
#pragma unroll
                for (int ni = 0; ni < 2; ++ni)
                    acc[mi][ni] = __builtin_amdgcn_mfma_f32_16x16x32_bf16(
                        a[mi], b[ni], acc[mi][ni], 0, 0, 0);
        }
        __syncthreads();
    }

    float* Cs = smemf;
#pragma unroll
    for (int ni = 0; ni < 2; ++ni) {
        const int nl = wn * 32 + ni * 16 + l16;
        const float bcol = bias[n0 + nl];
#pragma unroll
        for (int mi = 0; mi < 4; ++mi)
#pragma unroll
            for (int i = 0; i < 4; ++i) {
                const int ml = wm * 64 + mi * 16 + quad * 4 + i;
                Cs[ml * 66 + nl] = acc[mi][ni][i] + bcol;
            }
    }
    __syncthreads();
#pragma unroll
    for (int j = 0; j < 8; ++j) {
        int slot = j * 256 + tid;
        int rr = slot >> 4, cc = slot & 15;
        float4 v = *(const float4*)(Cs + rr * 66 + cc * 4);
        *(float4*)(C + (size_t)(m0 + rr) * DIM + n0 + cc * 4) = v;
    }
}

// ---------------------------------------------------------------------------
// MFMA flash attention, S^T formulation — NOW PIPELINED: f-chunk 64,
// K/V double-buffered in LDS, counted vmcnt (never 0 in steady state),
// builtin barriers, setprio around MFMA clusters. Per iter:
//   compute(buf cur) -> barrier -> stage(it+2 -> cur) -> vmcnt(4) -> barrier
// so each stage has a full iteration of compute to land (the previous
// structure drained vmcnt(0) at a __syncthreads right after issuing the
// stage — latency serially exposed every iteration; MfmaUtil 14%).
// Q arrives pre-scaled by 0.125 (folded into gemm_qkv, exact in bf16),
// so softmax is a bare __expf. LDS 41.7KB -> 3 blocks/CU (as before).
// ---------------------------------------------------------------------------
__global__ __launch_bounds__(256, 3) void attn_kernel(
    const bf16* Qg, const bf16* __restrict__ Kg, const bf16* __restrict__ Vtg,
    const unsigned long long* __restrict__ Mbits, bf16* Og)
{
    __shared__ bf16 Ks[2 * 64 * 64];    // [buf][f][d], 8-group XOR swizzle
    __shared__ bf16 Vts[2 * 64 * 64];   // [buf][d][f], 8-group XOR swizzle
    __shared__ bf16 Pt[64 * 72];        // [t][f], padded rows
    __shared__ float ls[64];            // l transpose

    const int tid  = threadIdx.x;
    const int lane = tid & 63;
    const int wave = tid >> 6;
    const int quad = lane >> 4;
    const int l16  = lane & 15;

    const int lin = blockIdx.x + 16 * (blockIdx.y + 16 * blockIdx.z);
    const int xcd = lin & 7;
    const int t   = lin >> 3;
    const int bh  = xcd * 8 + (t >> 4);
    const int b   = bh >> 4;
    const int h   = bh & 15;
    const int t0  = (t & 15) * 64;

    const size_t qrow0 = (size_t)b * TT + t0;
    const size_t krow0 = (size_t)b * FF;
    const int wbase = tid & ~63;
    const int myrow = wave * 16 + l16;   // this lane's t-row

    // Q fragments (B-operand: n=t=l16, k=d) direct from global
    const bf16* qptr = Qg + (qrow0 + myrow) * DIM + h * HD;
    short8 qb0 = *(const short8*)(qptr + quad * 8);
    short8 qb1 = *(const short8*)(qptr + 32 + quad * 8);

    // staging base pointers: thread covers row (tid>>3), swizzled 8-col group
    const int srow = tid >> 3;
    const int sg   = ((tid & 7) ^ (srow & 7)) * 8;
    const bf16* kS = Kg + (krow0 + srow) * DIM + h * HD + sg;
    const bf16* vS = Vtg + (size_t)(h * HD + srow) * MROWS + b * FF + sg;

#define STAGE_KV(BUF, IT) do { \
    const bf16* ks_ = kS + (size_t)((IT) * 64) * DIM; \
    const bf16* vs_ = vS + (IT) * 64; \
    bf16* kd_ = Ks + (BUF) * 4096 + wbase * 8; \
    bf16* vd_ = Vts + (BUF) * 4096 + wbase * 8; \
    async_copy16(ks_, kd_); \
    async_copy16(ks_ + (size_t)32 * DIM, kd_ + 2048); \
    async_copy16(vs_, vd_); \
    async_copy16(vs_ + (size_t)32 * MROWS, vd_ + 2048); \
} while (0)

    // mask: this lane's row, 1 word per iteration, software prefetch
    const unsigned long long* mrow = Mbits + (qrow0 + myrow) * FB;
    unsigned long long w = mrow[0];

    float lsum = 0.f;
    f32x4 oacc[4] = {};

    // prologue: stage iters 0 and 1; leave iter-1's 4 loads in flight
    STAGE_KV(0, 0);
    STAGE_KV(1, 1);
    asm volatile("s_waitcnt vmcnt(4)");
    BARRIER();

#pragma unroll 2
    for (int it = 0; it < 16; ++it) {
        const bf16* Kc = Ks + (it & 1) * 4096;
        const bf16* Vc = Vts + (it & 1) * 4096;

        // prefetch next iteration's mask word (hidden behind this iter)
        unsigned long long nw = (it < 15) ? mrow[it + 1] : 0;

        // S^T = K @ Q^T : 64 f-rows x 16 t-cols per wave (A=K, B=Q)
        f32x4 sacc[4];
        __builtin_amdgcn_s_setprio(1);
#pragma unroll
        for (int ft = 0; ft < 4; ++ft) {
            int r = ft * 16 + l16;
            short8 ka0 = *(const short8*)(Kc + r * 64 + ((quad       ^ (r & 7)) * 8));
            short8 ka1 = *(const short8*)(Kc + r * 64 + (((quad + 4) ^ (r & 7)) * 8));
            f32x4 s = {};
            s = __builtin_amdgcn_mfma_f32_16x16x32_bf16(ka0, qb0, s, 0, 0, 0);
            s = __builtin_amdgcn_mfma_f32_16x16x32_bf16(ka1, qb1, s, 0, 0, 0);
            sacc[ft] = s;
        }
        __builtin_amdgcn_s_setprio(0);

        // exp + mask + vectorized P writes (lane: t=myrow, f=ft*16+quad*4+i)
#pragma unroll
        for (int ft = 0; ft < 4; ++ft) {
            const unsigned bits4 =
                (unsigned)(w >> (ft * 16 + quad * 4)) & 0xFu;
            union { short4v v; short s[4]; } pk;
            float psum = 0.f;
#pragma unroll
            for (int i = 0; i < 4; ++i) {
                float p = (bits4 >> i) & 1u ? __expf(sacc[ft][i]) : 0.f;
                psum += p;
                pk.s[i] = (short)__bfloat16_as_ushort(__float2bfloat16(p));
            }
            lsum += psum;
            *(short4v*)(Pt + myrow * 72 + ft * 16 + quad * 4) = pk.v;
        }
        w = nw;

        // PV A-frags from own Pt rows (in-order same-wave LDS)
        short8 pa[2];
        pa[0] = *(const short8*)(Pt + myrow * 72 + quad * 8);
        pa[1] = *(const short8*)(Pt + myrow * 72 + 32 + quad * 8);
        __builtin_amdgcn_s_setprio(1);
#pragma unroll
        for (int nt = 0; nt < 4; ++nt) {
            int rd = nt * 16 + l16;
#pragma unroll
            for (int kf = 0; kf < 2; ++kf) {
                int g = (kf * 4 + quad) ^ (rd & 7);
                short8 vb = *(const short8*)(Vc + rd * 64 + g * 8);
                oacc[nt] = __builtin_amdgcn_mfma_f32_16x16x32_bf16(pa[kf], vb, oacc[nt], 0, 0, 0);
            }
        }
        __builtin_amdgcn_s_setprio(0);

        BARRIER();   // all waves done reading buf(it&1)
        if (it + 2 < 16) STAGE_KV(it & 1, it + 2);
        if (it < 14)       { asm volatile("s_waitcnt vmcnt(4)"); }
        else if (it == 14) { asm volatile("s_waitcnt vmcnt(0)"); }
        BARRIER();   // stage(it+1) visible to all waves
    }
#undef STAGE_KV

    // reduce l across quads (lanes sharing l16)
    lsum += __shfl_xor(lsum, 16);
    lsum += __shfl_xor(lsum, 32);
    if (quad == 0) ls[myrow] = lsum;   // same-wave readback below

    // epilogue: normalize (l for t=quad*4+i via ls) + coalesced store via Pt
#pragma unroll
    for (int i = 0; i < 4; ++i) {
        float inv = 1.0f / ls[wave * 16 + quad * 4 + i];
        const int prow = wave * 16 + quad * 4 + i;
#pragma unroll
        for (int nt = 0; nt < 4; ++nt)
            Pt[prow * 72 + nt * 16 + l16] = __float2bfloat16(oacc[nt][i] * inv);
    }
    __syncthreads();
#pragma unroll
    for (int j = 0; j < 2; ++j) {
        int s = j * 256 + tid;
        int rr = s >> 3, off = (s & 7) * 8;
        short8 v = *(const short8*)(Pt + rr * 72 + off);
        *(short8*)(Og + (qrow0 + rr) * DIM + h * HD + off) = v;
    }
}

// ---------------------------------------------------------------------------
extern "C" void kernel_launch(void* const* d_in, const int* in_sizes, int n_in,
                              void* d_out, int out_size, void* d_ws, size_t ws_size,
                              hipStream_t stream) {
    const float* X_to   = (const float*)d_in[0];
    const float* X_from = (const float*)d_in[1];
    const int*   mask   = (const int*)  d_in[2];
    const float* Wq     = (const float*)d_in[3];
    const float* bq     = (const float*)d_in[4];
    const float* Wk     = (const float*)d_in[5];
    const float* bk     = (const float*)d_in[6];
    const float* Wv     = (const float*)d_in[7];
    const float* bv     = (const float*)d_in[8];
    const float* Wo     = (const float*)d_in[9];
    const float* bo     = (const float*)d_in[10];
    float* out = (float*)d_out;

    char* ws = (char*)d_ws;
    bf16* Xt16 = (bf16*)(ws);
    bf16* Xf16 = (bf16*)(ws + (8u  << 20));
    bf16* Wq16 = (bf16*)(ws + (16u << 20));
    bf16* Wv16 = (bf16*)(ws + (18u << 20));
    bf16* Wk16 = (bf16*)(ws + (20u << 20));
    bf16* Wo16 = (bf16*)(ws + (22u << 20));
    bf16* Q16  = (bf16*)(ws + (24u << 20));
    bf16* K16  = (bf16*)(ws + (32u << 20));
    bf16* Vt16 = (bf16*)(ws + (40u << 20));
    unsigned long long* Mb = (unsigned long long*)(ws + (48u << 20));

    ConvArgs ca;
    ca.src[0] = X_to;   ca.dst[0] = Xt16; ca.nvec[0] = MROWS * DIM / 4;
    ca.src[1] = X_from; ca.dst[1] = Xf16; ca.nvec[1] = MROWS * DIM / 4;
    ca.src[2] = Wq;     ca.dst[2] = Wq16; ca.nvec[2] = DIM * DIM / 4;
    ca.src[3] = Wv;     ca.dst[3] = Wv16; ca.nvec[3] = DIM * DIM / 4;
    ca.src[4] = Wk;     ca.dst[4] = Wk16; ca.nvec[4] = DIM * DIM / 4;
    ca.src[5] = Wo;     ca.dst[5] = Wo16; ca.nvec[5] = DIM * DIM / 4;
    int cum = 0;
    for (int k = 0; k < 6; ++k) { cum += ca.nvec[k] / 256; ca.blk_end[k] = cum; }
    ca.mask = mask; ca.Mb = Mb;
    convert_pack<<<cum + 1024, 256, 0, stream>>>(ca);

    QkvArgs qa;
    qa.A[0] = Xt16; qa.W[0] = Wq16; qa.bias[0] = bq; qa.C[0] = Q16;
    qa.N[0] = DIM; qa.biasRow[0] = 0; qa.scale[0] = 0.125f;
    qa.A[1] = Xf16; qa.W[1] = Wv16; qa.bias[1] = bv; qa.C[1] = K16;
    qa.N[1] = DIM; qa.biasRow[1] = 0; qa.scale[1] = 1.0f;
    qa.A[2] = Wk16; qa.W[2] = Xf16; qa.bias[2] = bk; qa.C[2] = Vt16;
    qa.N[2] = MROWS; qa.biasRow[2] = 1; qa.scale[2] = 1.0f;
    gemm_qkv<<<dim3(64, 3), 512, 0, stream>>>(qa);

    attn_kernel<<<dim3(TT / 64, NH, BB), 256, 0, stream>>>(
        Q16, K16, Vt16, Mb, Q16);

    gemm_o<<<dim3(DIM / 64, MROWS / 128), 256, 0, stream>>>(Q16, Wo16, bo, out);
}

// Round 6
// 219.505 us; speedup vs baseline: 1.0258x; 1.0258x over previous
//
#include <hip/hip_runtime.h>
#include <hip/hip_bf16.h>
#include <math.h>

#define BB 4
#define TT 1024
#define FF 1024
#define DIM 1024
#define NH 16
#define HD 64
#define MROWS (BB * TT)   // 4096
#define FB (FF / 64)      // 16 uint64 mask words per row

typedef __attribute__((ext_vector_type(8))) short short8;
typedef __attribute__((ext_vector_type(4))) short short4v;
typedef __attribute__((ext_vector_type(4))) float f32x4;
typedef __hip_bfloat16 bf16;

__device__ __forceinline__ void async_copy16(const void* g, void* l) {
    __builtin_amdgcn_global_load_lds((const __attribute__((address_space(1))) void*)g,
                                     (__attribute__((address_space(3))) void*)l,
                                     16, 0, 0);
}

#define BARRIER() __builtin_amdgcn_s_barrier()

// ---------------------------------------------------------------------------
// Fused f32->bf16 convert (segments 0..5) + mask bit-pack (tail blocks).
// ---------------------------------------------------------------------------
struct ConvArgs {
    const float* src[6];
    bf16* dst[6];
    int nvec[6];
    int blk_end[6];
    const int* mask;
    unsigned long long* Mb;
};

__global__ __launch_bounds__(256) void convert_pack(ConvArgs a) {
    int bx = blockIdx.x;
    if (bx >= a.blk_end[5]) {
        const int lane = threadIdx.x & 63;
        const int waveId = (bx - a.blk_end[5]) * 4 + (threadIdx.x >> 6);
#pragma unroll
        for (int it = 0; it < 16; ++it) {
            int c = waveId * 16 + it;
            int v = a.mask[(size_t)c * 64 + lane];
            unsigned long long bits = __ballot(v != 0);
            if (lane == 0) a.Mb[c] = bits;
        }
        return;
    }
    int seg = 0;
#pragma unroll
    for (int k = 0; k < 5; ++k) if (bx >= a.blk_end[k]) seg = k + 1;
    int b0 = seg ? a.blk_end[seg - 1] : 0;
    int idx = (bx - b0) * 256 + threadIdx.x;
    if (idx >= a.nvec[seg]) return;
    float4 v = ((const float4*)a.src[seg])[idx];
    union { bf16 t[4]; ushort4 u; } o;
    o.t[0] = __float2bfloat16(v.x);
    o.t[1] = __float2bfloat16(v.y);
    o.t[2] = __float2bfloat16(v.z);
    o.t[3] = __float2bfloat16(v.w);
    *(ushort4*)(a.dst[seg] + 4 * (size_t)idx) = o.u;
}

// ---------------------------------------------------------------------------
// Fused Q/K/Vt projection GEMMs — 128x128 tiles (768 blocks, 2 blocks/CU
// co-resident at 64KB LDS), double-buffered, depth-2 prefetch, counted
// vmcnt. RACE FIX vs round 5: per-tile order is now
//   ds_reads -> MFMA (compiler lgkm waits = reads register-consumed)
//   -> BARRIER (all waves consumed buf) -> STAGE(t+2 -> same buf)
//   -> counted vmcnt -> BARRIER (stage(t+1) visible)
// Round 5 issued the overwriting STAGE after a barrier that only ordered
// ds_read ISSUE, not completion -> waves' pending ds_reads could read
// freshly-landed stage data (intermittent corruption, test FAILED).
// This ordering is isomorphic to the round-4 attn loop (measured correct).
// Q output pre-scaled by 0.125 (exact in bf16).
// ---------------------------------------------------------------------------
#define BK 64

struct QkvArgs {
    const bf16* A[3]; const bf16* W[3]; const float* bias[3]; bf16* C[3];
    int N[3]; int biasRow[3]; float scale[3];
};

__global__ __launch_bounds__(256, 2) void gemm_qkv(QkvArgs q) {
    __shared__ bf16 lds[32768];   // 64KB: buf b at b*16384 {A:0..8192, B:8192..16384}

    const int op = blockIdx.z;
    const bf16* A = q.A[op];
    const bf16* W = q.W[op];
    const float* bias = q.bias[op];
    bf16* C = q.C[op];
    const int N = q.N[op];
    const int brow = q.biasRow[op];
    const float sc = q.scale[op];

    const int lin = blockIdx.x + 8 * blockIdx.y;
    const int xcd = lin & 7;
    const int t8  = lin >> 3;
    int m0, n0;
    if (brow) {
        m0 = (((t8 & 7) + xcd) & 7) * 128;
        n0 = (xcd * 4 + (t8 >> 3)) * 128;
    } else {
        m0 = (xcd * 4 + (t8 >> 3)) * 128;
        n0 = (((t8 & 7) + xcd) & 7) * 128;
    }

    const int tid  = threadIdx.x;
    const int lane = tid & 63;
    const int wave = tid >> 6;
    const int quad = lane >> 4;
    const int l16  = lane & 15;
    const int wm = wave & 1;
    const int wn = wave >> 1;
    const int wbase = tid & ~63;

    // staging: thread covers row (tid>>3)+j*32, swizzled 8-elem K-group
    const int srow = tid >> 3;
    const int scol = (tid & 7) ^ (srow & 7);
    const bf16* pA = A + (size_t)(m0 + srow) * DIM + scol * 8;
    const bf16* pB = W + (size_t)(n0 + srow) * DIM + scol * 8;

#define STAGE(T) do { \
    const bf16* sa_ = pA + (size_t)(T) * 64; \
    const bf16* sb_ = pB + (size_t)(T) * 64; \
    bf16* base_ = lds + ((T) & 1) * 16384; \
    _Pragma("unroll") for (int j = 0; j < 4; ++j) { \
        async_copy16(sa_ + (size_t)(j * 32) * DIM, base_ + (j * 256 + wbase) * 8); \
        async_copy16(sb_ + (size_t)(j * 32) * DIM, base_ + 8192 + (j * 256 + wbase) * 8); \
    } \
} while (0)

    f32x4 acc[4][4] = {};

    // prologue: tiles 0 and 1 staged; keep tile-1's 8 loads in flight
    STAGE(0); STAGE(1);
    asm volatile("s_waitcnt vmcnt(8)");
    BARRIER();

#pragma unroll 2
    for (int t = 0; t < 16; ++t) {
        const bf16* As = lds + (t & 1) * 16384;
        const bf16* Bs = As + 8192;

        // ds_reads of the current tile; consumed by the MFMAs below, so the
        // compiler's lgkmcnt waits guarantee completion before the barrier.
        short8 a2[2][4], b2[2][4];
#pragma unroll
        for (int kk = 0; kk < 2; ++kk) {
#pragma unroll
            for (int mi = 0; mi < 4; ++mi) {
                int r = wm * 64 + mi * 16 + l16;
                int p = (kk * 4 + quad) ^ (r & 7);
                a2[kk][mi] = *(const short8*)(As + r * 64 + p * 8);
            }
#pragma unroll
            for (int ni = 0; ni < 4; ++ni) {
                int r = wn * 64 + ni * 16 + l16;
                int p = (kk * 4 + quad) ^ (r & 7);
                b2[kk][ni] = *(const short8*)(Bs + r * 64 + p * 8);
            }
        }
        __builtin_amdgcn_s_setprio(1);
#pragma unroll
        for (int kk = 0; kk < 2; ++kk)
#pragma unroll
            for (int mi = 0; mi < 4; ++mi)
#pragma unroll
                for (int ni = 0; ni < 4; ++ni)
                    acc[mi][ni] = __builtin_amdgcn_mfma_f32_16x16x32_bf16(
                        a2[kk][mi], b2[kk][ni], acc[mi][ni], 0, 0, 0);
        __builtin_amdgcn_s_setprio(0);

        BARRIER();   // every wave has register-consumed buf(t&1)
        if (t + 2 < 16) STAGE(t + 2);   // overwrite now provably safe
        // counted wait: completes stage(t+1) (oldest 8), leaves stage(t+2)
        if (t < 14)       { asm volatile("s_waitcnt vmcnt(8)"); }
        else if (t == 14) { asm volatile("s_waitcnt vmcnt(0)"); }
        BARRIER();   // stage(t+1) visible to all waves
    }

    // epilogue: bias + scale + bf16 convert into LDS, coalesced 16B stores
    bf16* Cs = lds;
#pragma unroll
    for (int ni = 0; ni < 4; ++ni) {
        const int nl = wn * 64 + ni * 16 + l16;
        float bcol = brow ? 0.0f : bias[n0 + nl];
#pragma unroll
        for (int mi = 0; mi < 4; ++mi)
#pragma unroll
            for (int i = 0; i < 4; ++i) {
                const int ml = wm * 64 + mi * 16 + quad * 4 + i;
                float v = (acc[mi][ni][i] + (brow ? bias[m0 + ml] : bcol)) * sc;
                Cs[ml * 132 + nl] = __float2bfloat16(v);
            }
    }
    __syncthreads();
#pragma unroll
    for (int j = 0; j < 8; ++j) {
        int slot = j * 256 + tid;
        int rr = slot >> 4, cc = slot & 15;
        short8 v = *(const short8*)(Cs + rr * 132 + cc * 8);
        *(short8*)(C + (size_t)(m0 + rr) * N + n0 + cc * 8) = v;
    }
#undef STAGE
}

// ---------------------------------------------------------------------------
// O-projection GEMM — same corrected pipelined structure (128x64 tile,
// dbuf 48KB, depth-2 prefetch after-consume, counted vmcnt(6), 512 blocks).
// ---------------------------------------------------------------------------
__global__ __launch_bounds__(256, 2) void gemm_o(
    const bf16* __restrict__ A, const bf16* __restrict__ W,
    const float* __restrict__ bias, float* __restrict__ C)
{
    __shared__ bf16 lds[24576];  // 48KB: A buf b at b*8192; B buf b at 16384+b*4096

    const int lin = blockIdx.x + 16 * blockIdx.y;
    const int xcd = lin & 7;
    const int t8  = lin >> 3;
    const int m0 = (xcd * 4 + (t8 >> 4)) * 128;
    const int n0 = (((t8 & 15) + 2 * xcd) & 15) * 64;

    const int tid  = threadIdx.x;
    const int lane = tid & 63;
    const int wave = tid >> 6;
    const int quad = lane >> 4;
    const int l16  = lane & 15;
    const int wm = wave & 1;
    const int wn = wave >> 1;
    const int wbase = tid & ~63;

    const int srow = tid >> 3;
    const int scol = (tid & 7) ^ (srow & 7);
    const bf16* pA = A + (size_t)(m0 + srow) * DIM + scol * 8;
    const bf16* pB = W + (size_t)(n0 + srow) * DIM + scol * 8;

#define STAGE_O(T) do { \
    const bf16* sa_ = pA + (size_t)(T) * 64; \
    const bf16* sb_ = pB + (size_t)(T) * 64; \
    bf16* ab_ = lds + ((T) & 1) * 8192; \
    bf16* bb_ = lds + 16384 + ((T) & 1) * 4096; \
    _Pragma("unroll") for (int j = 0; j < 4; ++j) \
        async_copy16(sa_ + (size_t)(j * 32) * DIM, ab_ + (j * 256 + wbase) * 8); \
    _Pragma("unroll") for (int j = 0; j < 2; ++j) \
        async_copy16(sb_ + (size_t)(j * 32) * DIM, bb_ + (j * 256 + wbase) * 8); \
} while (0)

    f32x4 acc[4][2] = {};

    STAGE_O(0); STAGE_O(1);
    asm volatile("s_waitcnt vmcnt(6)");
    BARRIER();

#pragma unroll 2
    for (int t = 0; t < 16; ++t) {
        const bf16* As = lds + (t & 1) * 8192;
        const bf16* Bs = lds + 16384 + (t & 1) * 4096;

        short8 a2[2][4], b2[2][2];
#pragma unroll
        for (int kk = 0; kk < 2; ++kk) {
#pragma unroll
            for (int mi = 0; mi < 4; ++mi) {
                int r = wm * 64 + mi * 16 + l16;
                int p = (kk * 4 + quad) ^ (r & 7);
                a2[kk][mi] = *(const short8*)(As + r * 64 + p * 8);
            }
#pragma unroll
            for (int ni = 0; ni < 2; ++ni) {
                int r = wn * 32 + ni * 16 + l16;
                int p = (kk * 4 + quad) ^ (r & 7);
                b2[kk][ni] = *(const short8*)(Bs + r * 64 + p * 8);
            }
        }
        __builtin_amdgcn_s_setprio(1);
#pragma unroll
        for (int kk = 0; kk < 2; ++kk)
#pragma unroll
            for (int mi = 0; mi < 4; ++mi)
#pragma unroll
                for (int ni = 0; ni < 2; ++ni)
                    acc[mi][ni] = __builtin_amdgcn_mfma_f32_16x16x32_bf16(
                        a2[kk][mi], b2[kk][ni], acc[mi][ni], 0, 0, 0);
        __builtin_amdgcn_s_setprio(0);

        BARRIER();   // reads consumed
        if (t + 2 < 16) STAGE_O(t + 2);
        if (t < 14)       { asm volatile("s_waitcnt vmcnt(6)"); }
        else if (t == 14) { asm volatile("s_waitcnt vmcnt(0)"); }
        BARRIER();   // stage(t+1) visible
    }

    float* Cs = (float*)lds;   // 128x66 f32 = 33.8KB <= 48KB
#pragma unroll
    for (int ni = 0; ni < 2; ++ni) {
        const int nl = wn * 32 + ni * 16 + l16;
        const float bcol = bias[n0 + nl];
#pragma unroll
        for (int mi = 0; mi < 4; ++mi)
#pragma unroll
            for (int i = 0; i < 4; ++i) {
                const int ml = wm * 64 + mi * 16 + quad * 4 + i;
                Cs[ml * 66 + nl] = acc[mi][ni][i] + bcol;
            }
    }
    __syncthreads();
#pragma unroll
    for (int j = 0; j < 8; ++j) {
        int slot = j * 256 + tid;
        int rr = slot >> 4, cc = slot & 15;
        float4 v = *(const float4*)(Cs + rr * 66 + cc * 4);
        *(float4*)(C + (size_t)(m0 + rr) * DIM + n0 + cc * 4) = v;
    }
#undef STAGE_O
}

// ---------------------------------------------------------------------------
// MFMA flash attention, S^T formulation, pipelined (unchanged from r4 — it
// already used the consume-then-overwrite ordering and measured correct).
// ---------------------------------------------------------------------------
__global__ __launch_bounds__(256, 3) void attn_kernel(
    const bf16* Qg, const bf16* __restrict__ Kg, const bf16* __restrict__ Vtg,
    const unsigned long long* __restrict__ Mbits, bf16* Og)
{
    __shared__ bf16 Ks[2 * 64 * 64];    // [buf][f][d], 8-group XOR swizzle
    __shared__ bf16 Vts[2 * 64 * 64];   // [buf][d][f], 8-group XOR swizzle
    __shared__ bf16 Pt[64 * 72];        // [t][f], padded rows
    __shared__ float ls[64];            // l transpose

    const int tid  = threadIdx.x;
    const int lane = tid & 63;
    const int wave = tid >> 6;
    const int quad = lane >> 4;
    const int l16  = lane & 15;

    const int lin = blockIdx.x + 16 * (blockIdx.y + 16 * blockIdx.z);
    const int xcd = lin & 7;
    const int t   = lin >> 3;
    const int bh  = xcd * 8 + (t >> 4);
    const int b   = bh >> 4;
    const int h   = bh & 15;
    const int t0  = (t & 15) * 64;

    const size_t qrow0 = (size_t)b * TT + t0;
    const size_t krow0 = (size_t)b * FF;
    const int wbase = tid & ~63;
    const int myrow = wave * 16 + l16;   // this lane's t-row

    // Q fragments (B-operand: n=t=l16, k=d) direct from global
    const bf16* qptr = Qg + (qrow0 + myrow) * DIM + h * HD;
    short8 qb0 = *(const short8*)(qptr + quad * 8);
    short8 qb1 = *(const short8*)(qptr + 32 + quad * 8);

    // staging base pointers: thread covers row (tid>>3), swizzled 8-col group
    const int srow = tid >> 3;
    const int sg   = ((tid & 7) ^ (srow & 7)) * 8;
    const bf16* kS = Kg + (krow0 + srow) * DIM + h * HD + sg;
    const bf16* vS = Vtg + (size_t)(h * HD + srow) * MROWS + b * FF + sg;

#define STAGE_KV(BUF, IT) do { \
    const bf16* ks_ = kS + (size_t)((IT) * 64) * DIM; \
    const bf16* vs_ = vS + (IT) * 64; \
    bf16* kd_ = Ks + (BUF) * 4096 + wbase * 8; \
    bf16* vd_ = Vts + (BUF) * 4096 + wbase * 8; \
    async_copy16(ks_, kd_); \
    async_copy16(ks_ + (size_t)32 * DIM, kd_ + 2048); \
    async_copy16(vs_, vd_); \
    async_copy16(vs_ + (size_t)32 * MROWS, vd_ + 2048); \
} while (0)

    // mask: this lane's row, 1 word per iteration, software prefetch
    const unsigned long long* mrow = Mbits + (qrow0 + myrow) * FB;
    unsigned long long w = mrow[0];

    float lsum = 0.f;
    f32x4 oacc[4] = {};

    // prologue: stage iters 0 and 1; leave iter-1's 4 loads in flight
    STAGE_KV(0, 0);
    STAGE_KV(1, 1);
    asm volatile("s_waitcnt vmcnt(4)");
    BARRIER();

#pragma unroll 2
    for (int it = 0; it < 16; ++it) {
        const bf16* Kc = Ks + (it & 1) * 4096;
        const bf16* Vc = Vts + (it & 1) * 4096;

        // prefetch next iteration's mask word (hidden behind this iter)
        unsigned long long nw = (it < 15) ? mrow[it + 1] : 0;

        // S^T = K @ Q^T : 64 f-rows x 16 t-cols per wave (A=K, B=Q)
        f32x4 sacc[4];
        __builtin_amdgcn_s_setprio(1);
#pragma unroll
        for (int ft = 0; ft < 4; ++ft) {
            int r = ft * 16 + l16;
            short8 ka0 = *(const short8*)(Kc + r * 64 + ((quad       ^ (r & 7)) * 8));
            short8 ka1 = *(const short8*)(Kc + r * 64 + (((quad + 4) ^ (r & 7)) * 8));
            f32x4 s = {};
            s = __builtin_amdgcn_mfma_f32_16x16x32_bf16(ka0, qb0, s, 0, 0, 0);
            s = __builtin_amdgcn_mfma_f32_16x16x32_bf16(ka1, qb1, s, 0, 0, 0);
            sacc[ft] = s;
        }
        __builtin_amdgcn_s_setprio(0);

        // exp + mask + vectorized P writes (lane: t=myrow, f=ft*16+quad*4+i)
#pragma unroll
        for (int ft = 0; ft < 4; ++ft) {
            const unsigned bits4 =
                (unsigned)(w >> (ft * 16 + quad * 4)) & 0xFu;
            union { short4v v; short s[4]; } pk;
            float psum = 0.f;
#pragma unroll
            for (int i = 0; i < 4; ++i) {
                float p = (bits4 >> i) & 1u ? __expf(sacc[ft][i]) : 0.f;
                psum += p;
                pk.s[i] = (short)__bfloat16_as_ushort(__float2bfloat16(p));
            }
            lsum += psum;
            *(short4v*)(Pt + myrow * 72 + ft * 16 + quad * 4) = pk.v;
        }
        w = nw;

        // PV A-frags from own Pt rows (in-order same-wave LDS)
        short8 pa[2];
        pa[0] = *(const short8*)(Pt + myrow * 72 + quad * 8);
        pa[1] = *(const short8*)(Pt + myrow * 72 + 32 + quad * 8);
        __builtin_amdgcn_s_setprio(1);
#pragma unroll
        for (int nt = 0; nt < 4; ++nt) {
            int rd = nt * 16 + l16;
#pragma unroll
            for (int kf = 0; kf < 2; ++kf) {
                int g = (kf * 4 + quad) ^ (rd & 7);
                short8 vb = *(const short8*)(Vc + rd * 64 + g * 8);
                oacc[nt] = __builtin_amdgcn_mfma_f32_16x16x32_bf16(pa[kf], vb, oacc[nt], 0, 0, 0);
            }
        }
        __builtin_amdgcn_s_setprio(0);

        BARRIER();   // all waves done reading buf(it&1)
        if (it + 2 < 16) STAGE_KV(it & 1, it + 2);
        if (it < 14)       { asm volatile("s_waitcnt vmcnt(4)"); }
        else if (it == 14) { asm volatile("s_waitcnt vmcnt(0)"); }
        BARRIER();   // stage(it+1) visible to all waves
    }
#undef STAGE_KV

    // reduce l across quads (lanes sharing l16)
    lsum += __shfl_xor(lsum, 16);
    lsum += __shfl_xor(lsum, 32);
    if (quad == 0) ls[myrow] = lsum;   // same-wave readback below

    // epilogue: normalize (l for t=quad*4+i via ls) + coalesced store via Pt
#pragma unroll
    for (int i = 0; i < 4; ++i) {
        float inv = 1.0f / ls[wave * 16 + quad * 4 + i];
        const int prow = wave * 16 + quad * 4 + i;
#pragma unroll
        for (int nt = 0; nt < 4; ++nt)
            Pt[prow * 72 + nt * 16 + l16] = __float2bfloat16(oacc[nt][i] * inv);
    }
    __syncthreads();
#pragma unroll
    for (int j = 0; j < 2; ++j) {
        int s = j * 256 + tid;
        int rr = s >> 3, off = (s & 7) * 8;
        short8 v = *(const short8*)(Pt + rr * 72 + off);
        *(short8*)(Og + (qrow0 + rr) * DIM + h * HD + off) = v;
    }
}

// ---------------------------------------------------------------------------
extern "C" void kernel_launch(void* const* d_in, const int* in_sizes, int n_in,
                              void* d_out, int out_size, void* d_ws, size_t ws_size,
                              hipStream_t stream) {
    const float* X_to   = (const float*)d_in[0];
    const float* X_from = (const float*)d_in[1];
    const int*   mask   = (const int*)  d_in[2];
    const float* Wq     = (const float*)d_in[3];
    const float* bq     = (const float*)d_in[4];
    const float* Wk     = (const float*)d_in[5];
    const float* bk     = (const float*)d_in[6];
    const float* Wv     = (const float*)d_in[7];
    const float* bv     = (const float*)d_in[8];
    const float* Wo     = (const float*)d_in[9];
    const float* bo     = (const float*)d_in[10];
    float* out = (float*)d_out;

    char* ws = (char*)d_ws;
    bf16* Xt16 = (bf16*)(ws);
    bf16* Xf16 = (bf16*)(ws + (8u  << 20));
    bf16* Wq16 = (bf16*)(ws + (16u << 20));
    bf16* Wv16 = (bf16*)(ws + (18u << 20));
    bf16* Wk16 = (bf16*)(ws + (20u << 20));
    bf16* Wo16 = (bf16*)(ws + (22u << 20));
    bf16* Q16  = (bf16*)(ws + (24u << 20));
    bf16* K16  = (bf16*)(ws + (32u << 20));
    bf16* Vt16 = (bf16*)(ws + (40u << 20));
    unsigned long long* Mb = (unsigned long long*)(ws + (48u << 20));

    ConvArgs ca;
    ca.src[0] = X_to;   ca.dst[0] = Xt16; ca.nvec[0] = MROWS * DIM / 4;
    ca.src[1] = X_from; ca.dst[1] = Xf16; ca.nvec[1] = MROWS * DIM / 4;
    ca.src[2] = Wq;     ca.dst[2] = Wq16; ca.nvec[2] = DIM * DIM / 4;
    ca.src[3] = Wv;     ca.dst[3] = Wv16; ca.nvec[3] = DIM * DIM / 4;
    ca.src[4] = Wk;     ca.dst[4] = Wk16; ca.nvec[4] = DIM * DIM / 4;
    ca.src[5] = Wo;     ca.dst[5] = Wo16; ca.nvec[5] = DIM * DIM / 4;
    int cum = 0;
    for (int k = 0; k < 6; ++k) { cum += ca.nvec[k] / 256; ca.blk_end[k] = cum; }
    ca.mask = mask; ca.Mb = Mb;
    convert_pack<<<cum + 1024, 256, 0, stream>>>(ca);

    QkvArgs qa;
    qa.A[0] = Xt16; qa.W[0] = Wq16; qa.bias[0] = bq; qa.C[0] = Q16;
    qa.N[0] = DIM; qa.biasRow[0] = 0; qa.scale[0] = 0.125f;
    qa.A[1] = Xf16; qa.W[1] = Wv16; qa.bias[1] = bv; qa.C[1] = K16;
    qa.N[1] = DIM; qa.biasRow[1] = 0; qa.scale[1] = 1.0f;
    qa.A[2] = Wk16; qa.W[2] = Xf16; qa.bias[2] = bk; qa.C[2] = Vt16;
    qa.N[2] = MROWS; qa.biasRow[2] = 1; qa.scale[2] = 1.0f;
    gemm_qkv<<<dim3(8, 32, 3), 256, 0, stream>>>(qa);

    attn_kernel<<<dim3(TT / 64, NH, BB), 256, 0, stream>>>(
        Q16, K16, Vt16, Mb, Q16);

    gemm_o<<<dim3(DIM / 64, MROWS / 128), 256, 0, stream>>>(Q16, Wo16, bo, out);
}

// Round 7
// 216.012 us; speedup vs baseline: 1.0424x; 1.0162x over previous
//
#include <hip/hip_runtime.h>
#include <hip/hip_bf16.h>
#include <math.h>

#define BB 4
#define TT 1024
#define FF 1024
#define DIM 1024
#define NH 16
#define HD 64
#define MROWS (BB * TT)   // 4096
#define FB (FF / 64)      // 16 uint64 mask words per row

typedef __attribute__((ext_vector_type(8))) short short8;
typedef __attribute__((ext_vector_type(4))) short short4v;
typedef __attribute__((ext_vector_type(4))) float f32x4;
typedef __hip_bfloat16 bf16;

__device__ __forceinline__ void async_copy16(const void* g, void* l) {
    __builtin_amdgcn_global_load_lds((const __attribute__((address_space(1))) void*)g,
                                     (__attribute__((address_space(3))) void*)l,
                                     16, 0, 0);
}

#define BARRIER() __builtin_amdgcn_s_barrier()

// ---------------------------------------------------------------------------
// Fused f32->bf16 convert (segments 0..5) + mask bit-pack (tail blocks).
// ---------------------------------------------------------------------------
struct ConvArgs {
    const float* src[6];
    bf16* dst[6];
    int nvec[6];
    int blk_end[6];
    const int* mask;
    unsigned long long* Mb;
};

__global__ __launch_bounds__(256) void convert_pack(ConvArgs a) {
    int bx = blockIdx.x;
    if (bx >= a.blk_end[5]) {
        const int lane = threadIdx.x & 63;
        const int waveId = (bx - a.blk_end[5]) * 4 + (threadIdx.x >> 6);
#pragma unroll
        for (int it = 0; it < 16; ++it) {
            int c = waveId * 16 + it;
            int v = a.mask[(size_t)c * 64 + lane];
            unsigned long long bits = __ballot(v != 0);
            if (lane == 0) a.Mb[c] = bits;
        }
        return;
    }
    int seg = 0;
#pragma unroll
    for (int k = 0; k < 5; ++k) if (bx >= a.blk_end[k]) seg = k + 1;
    int b0 = seg ? a.blk_end[seg - 1] : 0;
    int idx = (bx - b0) * 256 + threadIdx.x;
    if (idx >= a.nvec[seg]) return;
    float4 v = ((const float4*)a.src[seg])[idx];
    union { bf16 t[4]; ushort4 u; } o;
    o.t[0] = __float2bfloat16(v.x);
    o.t[1] = __float2bfloat16(v.y);
    o.t[2] = __float2bfloat16(v.z);
    o.t[3] = __float2bfloat16(v.w);
    *(ushort4*)(a.dst[seg] + 4 * (size_t)idx) = o.u;
}

// ---------------------------------------------------------------------------
// Fused Q/K/Vt projection GEMMs — 128x128 tiles, dbuf, depth-2 prefetch,
// counted vmcnt, consume-then-overwrite ordering (round-6, measured OK).
// ---------------------------------------------------------------------------
#define BK 64

struct QkvArgs {
    const bf16* A[3]; const bf16* W[3]; const float* bias[3]; bf16* C[3];
    int N[3]; int biasRow[3]; float scale[3];
};

__global__ __launch_bounds__(256, 2) void gemm_qkv(QkvArgs q) {
    __shared__ bf16 lds[32768];   // 64KB: buf b at b*16384 {A:0..8192, B:8192..16384}

    const int op = blockIdx.z;
    const bf16* A = q.A[op];
    const bf16* W = q.W[op];
    const float* bias = q.bias[op];
    bf16* C = q.C[op];
    const int N = q.N[op];
    const int brow = q.biasRow[op];
    const float sc = q.scale[op];

    const int lin = blockIdx.x + 8 * blockIdx.y;
    const int xcd = lin & 7;
    const int t8  = lin >> 3;
    int m0, n0;
    if (brow) {
        m0 = (((t8 & 7) + xcd) & 7) * 128;
        n0 = (xcd * 4 + (t8 >> 3)) * 128;
    } else {
        m0 = (xcd * 4 + (t8 >> 3)) * 128;
        n0 = (((t8 & 7) + xcd) & 7) * 128;
    }

    const int tid  = threadIdx.x;
    const int lane = tid & 63;
    const int wave = tid >> 6;
    const int quad = lane >> 4;
    const int l16  = lane & 15;
    const int wm = wave & 1;
    const int wn = wave >> 1;
    const int wbase = tid & ~63;

    const int srow = tid >> 3;
    const int scol = (tid & 7) ^ (srow & 7);
    const bf16* pA = A + (size_t)(m0 + srow) * DIM + scol * 8;
    const bf16* pB = W + (size_t)(n0 + srow) * DIM + scol * 8;

#define STAGE(T) do { \
    const bf16* sa_ = pA + (size_t)(T) * 64; \
    const bf16* sb_ = pB + (size_t)(T) * 64; \
    bf16* base_ = lds + ((T) & 1) * 16384; \
    _Pragma("unroll") for (int j = 0; j < 4; ++j) { \
        async_copy16(sa_ + (size_t)(j * 32) * DIM, base_ + (j * 256 + wbase) * 8); \
        async_copy16(sb_ + (size_t)(j * 32) * DIM, base_ + 8192 + (j * 256 + wbase) * 8); \
    } \
} while (0)

    f32x4 acc[4][4] = {};

    STAGE(0); STAGE(1);
    asm volatile("s_waitcnt vmcnt(8)");
    BARRIER();

#pragma unroll 2
    for (int t = 0; t < 16; ++t) {
        const bf16* As = lds + (t & 1) * 16384;
        const bf16* Bs = As + 8192;

        short8 a2[2][4], b2[2][4];
#pragma unroll
        for (int kk = 0; kk < 2; ++kk) {
#pragma unroll
            for (int mi = 0; mi < 4; ++mi) {
                int r = wm * 64 + mi * 16 + l16;
                int p = (kk * 4 + quad) ^ (r & 7);
                a2[kk][mi] = *(const short8*)(As + r * 64 + p * 8);
            }
#pragma unroll
            for (int ni = 0; ni < 4; ++ni) {
                int r = wn * 64 + ni * 16 + l16;
                int p = (kk * 4 + quad) ^ (r & 7);
                b2[kk][ni] = *(const short8*)(Bs + r * 64 + p * 8);
            }
        }
        __builtin_amdgcn_s_setprio(1);
#pragma unroll
        for (int kk = 0; kk < 2; ++kk)
#pragma unroll
            for (int mi = 0; mi < 4; ++mi)
#pragma unroll
                for (int ni = 0; ni < 4; ++ni)
                    acc[mi][ni] = __builtin_amdgcn_mfma_f32_16x16x32_bf16(
                        a2[kk][mi], b2[kk][ni], acc[mi][ni], 0, 0, 0);
        __builtin_amdgcn_s_setprio(0);

        BARRIER();   // every wave has register-consumed buf(t&1)
        if (t + 2 < 16) STAGE(t + 2);
        if (t < 14)       { asm volatile("s_waitcnt vmcnt(8)"); }
        else if (t == 14) { asm volatile("s_waitcnt vmcnt(0)"); }
        BARRIER();
    }

    bf16* Cs = lds;
#pragma unroll
    for (int ni = 0; ni < 4; ++ni) {
        const int nl = wn * 64 + ni * 16 + l16;
        float bcol = brow ? 0.0f : bias[n0 + nl];
#pragma unroll
        for (int mi = 0; mi < 4; ++mi)
#pragma unroll
            for (int i = 0; i < 4; ++i) {
                const int ml = wm * 64 + mi * 16 + quad * 4 + i;
                float v = (acc[mi][ni][i] + (brow ? bias[m0 + ml] : bcol)) * sc;
                Cs[ml * 132 + nl] = __float2bfloat16(v);
            }
    }
    __syncthreads();
#pragma unroll
    for (int j = 0; j < 8; ++j) {
        int slot = j * 256 + tid;
        int rr = slot >> 4, cc = slot & 15;
        short8 v = *(const short8*)(Cs + rr * 132 + cc * 8);
        *(short8*)(C + (size_t)(m0 + rr) * N + n0 + cc * 8) = v;
    }
#undef STAGE
}

// ---------------------------------------------------------------------------
// O-projection GEMM (round-6 structure, measured OK).
// ---------------------------------------------------------------------------
__global__ __launch_bounds__(256, 2) void gemm_o(
    const bf16* __restrict__ A, const bf16* __restrict__ W,
    const float* __restrict__ bias, float* __restrict__ C)
{
    __shared__ bf16 lds[24576];  // 48KB

    const int lin = blockIdx.x + 16 * blockIdx.y;
    const int xcd = lin & 7;
    const int t8  = lin >> 3;
    const int m0 = (xcd * 4 + (t8 >> 4)) * 128;
    const int n0 = (((t8 & 15) + 2 * xcd) & 15) * 64;

    const int tid  = threadIdx.x;
    const int lane = tid & 63;
    const int wave = tid >> 6;
    const int quad = lane >> 4;
    const int l16  = lane & 15;
    const int wm = wave & 1;
    const int wn = wave >> 1;
    const int wbase = tid & ~63;

    const int srow = tid >> 3;
    const int scol = (tid & 7) ^ (srow & 7);
    const bf16* pA = A + (size_t)(m0 + srow) * DIM + scol * 8;
    const bf16* pB = W + (size_t)(n0 + srow) * DIM + scol * 8;

#define STAGE_O(T) do { \
    const bf16* sa_ = pA + (size_t)(T) * 64; \
    const bf16* sb_ = pB + (size_t)(T) * 64; \
    bf16* ab_ = lds + ((T) & 1) * 8192; \
    bf16* bb_ = lds + 16384 + ((T) & 1) * 4096; \
    _Pragma("unroll") for (int j = 0; j < 4; ++j) \
        async_copy16(sa_ + (size_t)(j * 32) * DIM, ab_ + (j * 256 + wbase) * 8); \
    _Pragma("unroll") for (int j = 0; j < 2; ++j) \
        async_copy16(sb_ + (size_t)(j * 32) * DIM, bb_ + (j * 256 + wbase) * 8); \
} while (0)

    f32x4 acc[4][2] = {};

    STAGE_O(0); STAGE_O(1);
    asm volatile("s_waitcnt vmcnt(6)");
    BARRIER();

#pragma unroll 2
    for (int t = 0; t < 16; ++t) {
        const bf16* As = lds + (t & 1) * 8192;
        const bf16* Bs = lds + 16384 + (t & 1) * 4096;

        short8 a2[2][4], b2[2][2];
#pragma unroll
        for (int kk = 0; kk < 2; ++kk) {
#pragma unroll
            for (int mi = 0; mi < 4; ++mi) {
                int r = wm * 64 + mi * 16 + l16;
                int p = (kk * 4 + quad) ^ (r & 7);
                a2[kk][mi] = *(const short8*)(As + r * 64 + p * 8);
            }
#pragma unroll
            for (int ni = 0; ni < 2; ++ni) {
                int r = wn * 32 + ni * 16 + l16;
                int p = (kk * 4 + quad) ^ (r & 7);
                b2[kk][ni] = *(const short8*)(Bs + r * 64 + p * 8);
            }
        }
        __builtin_amdgcn_s_setprio(1);
#pragma unroll
        for (int kk = 0; kk < 2; ++kk)
#pragma unroll
            for (int mi = 0; mi < 4; ++mi)
#pragma unroll
                for (int ni = 0; ni < 2; ++ni)
                    acc[mi][ni] = __builtin_amdgcn_mfma_f32_16x16x32_bf16(
                        a2[kk][mi], b2[kk][ni], acc[mi][ni], 0, 0, 0);
        __builtin_amdgcn_s_setprio(0);

        BARRIER();
        if (t + 2 < 16) STAGE_O(t + 2);
        if (t < 14)       { asm volatile("s_waitcnt vmcnt(6)"); }
        else if (t == 14) { asm volatile("s_waitcnt vmcnt(0)"); }
        BARRIER();
    }

    float* Cs = (float*)lds;
#pragma unroll
    for (int ni = 0; ni < 2; ++ni) {
        const int nl = wn * 32 + ni * 16 + l16;
        const float bcol = bias[n0 + nl];
#pragma unroll
        for (int mi = 0; mi < 4; ++mi)
#pragma unroll
            for (int i = 0; i < 4; ++i) {
                const int ml = wm * 64 + mi * 16 + quad * 4 + i;
                Cs[ml * 66 + nl] = acc[mi][ni][i] + bcol;
            }
    }
    __syncthreads();
#pragma unroll
    for (int j = 0; j < 8; ++j) {
        int slot = j * 256 + tid;
        int rr = slot >> 4, cc = slot & 15;
        float4 v = *(const float4*)(Cs + rr * 66 + cc * 4);
        *(float4*)(C + (size_t)(m0 + rr) * DIM + n0 + cc * 4) = v;
    }
#undef STAGE_O
}

// ---------------------------------------------------------------------------
// MFMA flash attention — T15 double-pipeline: QK^T(it+1) issues BEFORE
// softmax(it), so the 8 QK MFMAs (matrix pipe) overlap the softmax VALU
// within each wave (the old body was a serial QK->SM->PV chain; at 3
// blocks/CU the idle fraction was ~45%). K is TRIPLE-buffered (QK reads
// chunk it+1 during iter it, so K stages 3 ahead); V stays double.
// Ledger: K-stage(c)@iter c-3 (2-iter window), V-stage(c)@iter c-2
// (2-iter window); in-flight entering iter j = K(j+2)+V(j+1) = 4 loads ->
// steady vmcnt(4); tail j=13:vmcnt(2), j=14:vmcnt(0). Slot reuse: every
// region's last reader is >=1 barrier before its overwrite:
//   K slot (c%3): chunk c-3 last read (QK-next) at iter c-4; staged at c-3.
//   V slot (c&1): chunk c-2 last read (PV) at iter c-2 pre-barrier; staged
//   at c-2 post-barrier.  LDS 49.3KB -> still 3 blocks/CU.
// No setprio around QK-next (compiler must be free to interleave softmax
// under it); setprio kept on PV cluster.
// ---------------------------------------------------------------------------
__global__ __launch_bounds__(256, 3) void attn_kernel(
    const bf16* Qg, const bf16* __restrict__ Kg, const bf16* __restrict__ Vtg,
    const unsigned long long* __restrict__ Mbits, bf16* Og)
{
    __shared__ bf16 Ks[3 * 64 * 64];    // [slot c%3][f][d], 8-group XOR swizzle
    __shared__ bf16 Vts[2 * 64 * 64];   // [slot c&1][d][f], 8-group XOR swizzle
    __shared__ bf16 Pt[64 * 72];        // [t][f], padded rows
    __shared__ float ls[64];            // l transpose

    const int tid  = threadIdx.x;
    const int lane = tid & 63;
    const int wave = tid >> 6;
    const int quad = lane >> 4;
    const int l16  = lane & 15;

    const int lin = blockIdx.x + 16 * (blockIdx.y + 16 * blockIdx.z);
    const int xcd = lin & 7;
    const int t   = lin >> 3;
    const int bh  = xcd * 8 + (t >> 4);
    const int b   = bh >> 4;
    const int h   = bh & 15;
    const int t0  = (t & 15) * 64;

    const size_t qrow0 = (size_t)b * TT + t0;
    const size_t krow0 = (size_t)b * FF;
    const int wbase = tid & ~63;
    const int myrow = wave * 16 + l16;   // this lane's t-row

    // Q fragments (B-operand: n=t=l16, k=d) direct from global
    const bf16* qptr = Qg + (qrow0 + myrow) * DIM + h * HD;
    short8 qb0 = *(const short8*)(qptr + quad * 8);
    short8 qb1 = *(const short8*)(qptr + 32 + quad * 8);

    // staging base pointers: thread covers row (tid>>3), swizzled 8-col group
    const int srow = tid >> 3;
    const int sg   = ((tid & 7) ^ (srow & 7)) * 8;
    const bf16* kS = Kg + (krow0 + srow) * DIM + h * HD + sg;
    const bf16* vS = Vtg + (size_t)(h * HD + srow) * MROWS + b * FF + sg;

#define STAGE_K(SLOT, IT) do { \
    const bf16* ks_ = kS + (size_t)((IT) * 64) * DIM; \
    bf16* kd_ = Ks + (SLOT) * 4096 + wbase * 8; \
    async_copy16(ks_, kd_); \
    async_copy16(ks_ + (size_t)32 * DIM, kd_ + 2048); \
} while (0)

#define STAGE_V(SLOT, IT) do { \
    const bf16* vs_ = vS + (IT) * 64; \
    bf16* vd_ = Vts + (SLOT) * 4096 + wbase * 8; \
    async_copy16(vs_, vd_); \
    async_copy16(vs_ + (size_t)32 * MROWS, vd_ + 2048); \
} while (0)

#define QK_CLUSTER(DST, KPTR) do { \
    _Pragma("unroll") for (int ft = 0; ft < 4; ++ft) { \
        int r_ = ft * 16 + l16; \
        short8 ka0 = *(const short8*)((KPTR) + r_ * 64 + ((quad       ^ (r_ & 7)) * 8)); \
        short8 ka1 = *(const short8*)((KPTR) + r_ * 64 + (((quad + 4) ^ (r_ & 7)) * 8)); \
        f32x4 s_ = {}; \
        s_ = __builtin_amdgcn_mfma_f32_16x16x32_bf16(ka0, qb0, s_, 0, 0, 0); \
        s_ = __builtin_amdgcn_mfma_f32_16x16x32_bf16(ka1, qb1, s_, 0, 0, 0); \
        (DST)[ft] = s_; \
    } \
} while (0)

    // mask: this lane's row, 1 word per iteration, software prefetch
    const unsigned long long* mrow = Mbits + (qrow0 + myrow) * FB;
    unsigned long long w = mrow[0];

    float lsum = 0.f;
    f32x4 oacc[4] = {};

    // prologue: K(0),K(1),V(0) must land; K(2),V(1) stay in flight (4 loads)
    STAGE_K(0, 0); STAGE_K(1, 1); STAGE_V(0, 0);
    STAGE_K(2, 2); STAGE_V(1, 1);
    asm volatile("s_waitcnt vmcnt(4)");
    BARRIER();

    // initial QK for chunk 0
    f32x4 scur[4];
    QK_CLUSTER(scur, Ks);

#pragma unroll 2
    for (int it = 0; it < 16; ++it) {
        const bf16* Vc = Vts + (it & 1) * 4096;

        // prefetch next iteration's mask word
        unsigned long long nw = (it < 15) ? mrow[it + 1] : 0;

        // QK^T for chunk it+1 (matrix pipe) — issued before softmax so the
        // compiler interleaves the VALU below under the MFMA latency.
        f32x4 snxt[4] = {};
        if (it < 15) {
            const bf16* Kn = Ks + ((it + 1) % 3) * 4096;
            QK_CLUSTER(snxt, Kn);
        }

        // softmax on scur: exp + mask + vectorized P writes (VALU pipe)
#pragma unroll
        for (int ft = 0; ft < 4; ++ft) {
            const unsigned bits4 =
                (unsigned)(w >> (ft * 16 + quad * 4)) & 0xFu;
            union { short4v v; short s[4]; } pk;
            float psum = 0.f;
#pragma unroll
            for (int i = 0; i < 4; ++i) {
                float p = (bits4 >> i) & 1u ? __expf(scur[ft][i]) : 0.f;
                psum += p;
                pk.s[i] = (short)__bfloat16_as_ushort(__float2bfloat16(p));
            }
            lsum += psum;
            *(short4v*)(Pt + myrow * 72 + ft * 16 + quad * 4) = pk.v;
        }
        w = nw;

        // PV A-frags from own Pt rows (in-order same-wave LDS)
        short8 pa[2];
        pa[0] = *(const short8*)(Pt + myrow * 72 + quad * 8);
        pa[1] = *(const short8*)(Pt + myrow * 72 + 32 + quad * 8);
        __builtin_amdgcn_s_setprio(1);
#pragma unroll
        for (int nt = 0; nt < 4; ++nt) {
            int rd = nt * 16 + l16;
#pragma unroll
            for (int kf = 0; kf < 2; ++kf) {
                int g = (kf * 4 + quad) ^ (rd & 7);
                short8 vb = *(const short8*)(Vc + rd * 64 + g * 8);
                oacc[nt] = __builtin_amdgcn_mfma_f32_16x16x32_bf16(pa[kf], vb, oacc[nt], 0, 0, 0);
            }
        }
        __builtin_amdgcn_s_setprio(0);

        BARRIER();   // all waves done reading K(it+1), V(it)
        if (it + 3 < 16) STAGE_K((it + 3) % 3, it + 3);
        if (it + 2 < 16) STAGE_V((it + 2) & 1, it + 2);
        if (it < 13)       { asm volatile("s_waitcnt vmcnt(4)"); }
        else if (it == 13) { asm volatile("s_waitcnt vmcnt(2)"); }
        else if (it == 14) { asm volatile("s_waitcnt vmcnt(0)"); }
        BARRIER();   // staged chunks visible to all waves

        scur[0] = snxt[0]; scur[1] = snxt[1];
        scur[2] = snxt[2]; scur[3] = snxt[3];
    }
#undef STAGE_K
#undef STAGE_V
#undef QK_CLUSTER

    // reduce l across quads (lanes sharing l16)
    lsum += __shfl_xor(lsum, 16);
    lsum += __shfl_xor(lsum, 32);
    if (quad == 0) ls[myrow] = lsum;   // same-wave readback below

    // epilogue: normalize (l for t=quad*4+i via ls) + coalesced store via Pt
#pragma unroll
    for (int i = 0; i < 4; ++i) {
        float inv = 1.0f / ls[wave * 16 + quad * 4 + i];
        const int prow = wave * 16 + quad * 4 + i;
#pragma unroll
        for (int nt = 0; nt < 4; ++nt)
            Pt[prow * 72 + nt * 16 + l16] = __float2bfloat16(oacc[nt][i] * inv);
    }
    __syncthreads();
#pragma unroll
    for (int j = 0; j < 2; ++j) {
        int s = j * 256 + tid;
        int rr = s >> 3, off = (s & 7) * 8;
        short8 v = *(const short8*)(Pt + rr * 72 + off);
        *(short8*)(Og + (qrow0 + rr) * DIM + h * HD + off) = v;
    }
}

// ---------------------------------------------------------------------------
extern "C" void kernel_launch(void* const* d_in, const int* in_sizes, int n_in,
                              void* d_out, int out_size, void* d_ws, size_t ws_size,
                              hipStream_t stream) {
    const float* X_to   = (const float*)d_in[0];
    const float* X_from = (const float*)d_in[1];
    const int*   mask   = (const int*)  d_in[2];
    const float* Wq     = (const float*)d_in[3];
    const float* bq     = (const float*)d_in[4];
    const float* Wk     = (const float*)d_in[5];
    const float* bk     = (const float*)d_in[6];
    const float* Wv     = (const float*)d_in[7];
    const float* bv     = (const float*)d_in[8];
    const float* Wo     = (const float*)d_in[9];
    const float* bo     = (const float*)d_in[10];
    float* out = (float*)d_out;

    char* ws = (char*)d_ws;
    bf16* Xt16 = (bf16*)(ws);
    bf16* Xf16 = (bf16*)(ws + (8u  << 20));
    bf16* Wq16 = (bf16*)(ws + (16u << 20));
    bf16* Wv16 = (bf16*)(ws + (18u << 20));
    bf16* Wk16 = (bf16*)(ws + (20u << 20));
    bf16* Wo16 = (bf16*)(ws + (22u << 20));
    bf16* Q16  = (bf16*)(ws + (24u << 20));
    bf16* K16  = (bf16*)(ws + (32u << 20));
    bf16* Vt16 = (bf16*)(ws + (40u << 20));
    unsigned long long* Mb = (unsigned long long*)(ws + (48u << 20));

    ConvArgs ca;
    ca.src[0] = X_to;   ca.dst[0] = Xt16; ca.nvec[0] = MROWS * DIM / 4;
    ca.src[1] = X_from; ca.dst[1] = Xf16; ca.nvec[1] = MROWS * DIM / 4;
    ca.src[2] = Wq;     ca.dst[2] = Wq16; ca.nvec[2] = DIM * DIM / 4;
    ca.src[3] = Wv;     ca.dst[3] = Wv16; ca.nvec[3] = DIM * DIM / 4;
    ca.src[4] = Wk;     ca.dst[4] = Wk16; ca.nvec[4] = DIM * DIM / 4;
    ca.src[5] = Wo;     ca.dst[5] = Wo16; ca.nvec[5] = DIM * DIM / 4;
    int cum = 0;
    for (int k = 0; k < 6; ++k) { cum += ca.nvec[k] / 256; ca.blk_end[k] = cum; }
    ca.mask = mask; ca.Mb = Mb;
    convert_pack<<<cum + 1024, 256, 0, stream>>>(ca);

    QkvArgs qa;
    qa.A[0] = Xt16; qa.W[0] = Wq16; qa.bias[0] = bq; qa.C[0] = Q16;
    qa.N[0] = DIM; qa.biasRow[0] = 0; qa.scale[0] = 0.125f;
    qa.A[1] = Xf16; qa.W[1] = Wv16; qa.bias[1] = bv; qa.C[1] = K16;
    qa.N[1] = DIM; qa.biasRow[1] = 0; qa.scale[1] = 1.0f;
    qa.A[2] = Wk16; qa.W[2] = Xf16; qa.bias[2] = bk; qa.C[2] = Vt16;
    qa.N[2] = MROWS; qa.biasRow[2] = 1; qa.scale[2] = 1.0f;
    gemm_qkv<<<dim3(8, 32, 3), 256, 0, stream>>>(qa);

    attn_kernel<<<dim3(TT / 64, NH, BB), 256, 0, stream>>>(
        Q16, K16, Vt16, Mb, Q16);

    gemm_o<<<dim3(DIM / 64, MROWS / 128), 256, 0, stream>>>(Q16, Wo16, bo, out);
}

// Round 8
// 205.464 us; speedup vs baseline: 1.0959x; 1.0513x over previous
//
#include <hip/hip_runtime.h>
#include <hip/hip_bf16.h>
#include <math.h>

#define BB 4
#define TT 1024
#define FF 1024
#define DIM 1024
#define NH 16
#define HD 64
#define MROWS (BB * TT)   // 4096
#define FB (FF / 64)      // 16 uint64 mask words per row

typedef __attribute__((ext_vector_type(8))) short short8;
typedef __attribute__((ext_vector_type(4))) short short4v;
typedef __attribute__((ext_vector_type(4))) float f32x4;
typedef __hip_bfloat16 bf16;

__device__ __forceinline__ void async_copy16(const void* g, void* l) {
    __builtin_amdgcn_global_load_lds((const __attribute__((address_space(1))) void*)g,
                                     (__attribute__((address_space(3))) void*)l,
                                     16, 0, 0);
}

#define BARRIER() __builtin_amdgcn_s_barrier()

// ---------------------------------------------------------------------------
// Fused f32->bf16 convert (segments 0..5) + mask bit-pack (tail blocks).
// ---------------------------------------------------------------------------
struct ConvArgs {
    const float* src[6];
    bf16* dst[6];
    int nvec[6];
    int blk_end[6];
    const int* mask;
    unsigned long long* Mb;
};

__global__ __launch_bounds__(256) void convert_pack(ConvArgs a) {
    int bx = blockIdx.x;
    if (bx >= a.blk_end[5]) {
        const int lane = threadIdx.x & 63;
        const int waveId = (bx - a.blk_end[5]) * 4 + (threadIdx.x >> 6);
#pragma unroll
        for (int it = 0; it < 16; ++it) {
            int c = waveId * 16 + it;
            int v = a.mask[(size_t)c * 64 + lane];
            unsigned long long bits = __ballot(v != 0);
            if (lane == 0) a.Mb[c] = bits;
        }
        return;
    }
    int seg = 0;
#pragma unroll
    for (int k = 0; k < 5; ++k) if (bx >= a.blk_end[k]) seg = k + 1;
    int b0 = seg ? a.blk_end[seg - 1] : 0;
    int idx = (bx - b0) * 256 + threadIdx.x;
    if (idx >= a.nvec[seg]) return;
    float4 v = ((const float4*)a.src[seg])[idx];
    union { bf16 t[4]; ushort4 u; } o;
    o.t[0] = __float2bfloat16(v.x);
    o.t[1] = __float2bfloat16(v.y);
    o.t[2] = __float2bfloat16(v.z);
    o.t[3] = __float2bfloat16(v.w);
    *(ushort4*)(a.dst[seg] + 4 * (size_t)idx) = o.u;
}

// ---------------------------------------------------------------------------
// Fused Q/K/Vt projection GEMMs — 128x128 tiles, dbuf, depth-2 prefetch,
// counted vmcnt, consume-then-overwrite ordering (round-6, measured OK).
// ---------------------------------------------------------------------------
#define BK 64

struct QkvArgs {
    const bf16* A[3]; const bf16* W[3]; const float* bias[3]; bf16* C[3];
    int N[3]; int biasRow[3]; float scale[3];
};

__global__ __launch_bounds__(256, 2) void gemm_qkv(QkvArgs q) {
    __shared__ bf16 lds[32768];   // 64KB: buf b at b*16384 {A:0..8192, B:8192..16384}

    const int op = blockIdx.z;
    const bf16* A = q.A[op];
    const bf16* W = q.W[op];
    const float* bias = q.bias[op];
    bf16* C = q.C[op];
    const int N = q.N[op];
    const int brow = q.biasRow[op];
    const float sc = q.scale[op];

    const int lin = blockIdx.x + 8 * blockIdx.y;
    const int xcd = lin & 7;
    const int t8  = lin >> 3;
    int m0, n0;
    if (brow) {
        m0 = (((t8 & 7) + xcd) & 7) * 128;
        n0 = (xcd * 4 + (t8 >> 3)) * 128;
    } else {
        m0 = (xcd * 4 + (t8 >> 3)) * 128;
        n0 = (((t8 & 7) + xcd) & 7) * 128;
    }

    const int tid  = threadIdx.x;
    const int lane = tid & 63;
    const int wave = tid >> 6;
    const int quad = lane >> 4;
    const int l16  = lane & 15;
    const int wm = wave & 1;
    const int wn = wave >> 1;
    const int wbase = tid & ~63;

    const int srow = tid >> 3;
    const int scol = (tid & 7) ^ (srow & 7);
    const bf16* pA = A + (size_t)(m0 + srow) * DIM + scol * 8;
    const bf16* pB = W + (size_t)(n0 + srow) * DIM + scol * 8;

#define STAGE(T) do { \
    const bf16* sa_ = pA + (size_t)(T) * 64; \
    const bf16* sb_ = pB + (size_t)(T) * 64; \
    bf16* base_ = lds + ((T) & 1) * 16384; \
    _Pragma("unroll") for (int j = 0; j < 4; ++j) { \
        async_copy16(sa_ + (size_t)(j * 32) * DIM, base_ + (j * 256 + wbase) * 8); \
        async_copy16(sb_ + (size_t)(j * 32) * DIM, base_ + 8192 + (j * 256 + wbase) * 8); \
    } \
} while (0)

    f32x4 acc[4][4] = {};

    STAGE(0); STAGE(1);
    asm volatile("s_waitcnt vmcnt(8)");
    BARRIER();

#pragma unroll 2
    for (int t = 0; t < 16; ++t) {
        const bf16* As = lds + (t & 1) * 16384;
        const bf16* Bs = As + 8192;

        short8 a2[2][4], b2[2][4];
#pragma unroll
        for (int kk = 0; kk < 2; ++kk) {
#pragma unroll
            for (int mi = 0; mi < 4; ++mi) {
                int r = wm * 64 + mi * 16 + l16;
                int p = (kk * 4 + quad) ^ (r & 7);
                a2[kk][mi] = *(const short8*)(As + r * 64 + p * 8);
            }
#pragma unroll
            for (int ni = 0; ni < 4; ++ni) {
                int r = wn * 64 + ni * 16 + l16;
                int p = (kk * 4 + quad) ^ (r & 7);
                b2[kk][ni] = *(const short8*)(Bs + r * 64 + p * 8);
            }
        }
        __builtin_amdgcn_s_setprio(1);
#pragma unroll
        for (int kk = 0; kk < 2; ++kk)
#pragma unroll
            for (int mi = 0; mi < 4; ++mi)
#pragma unroll
                for (int ni = 0; ni < 4; ++ni)
                    acc[mi][ni] = __builtin_amdgcn_mfma_f32_16x16x32_bf16(
                        a2[kk][mi], b2[kk][ni], acc[mi][ni], 0, 0, 0);
        __builtin_amdgcn_s_setprio(0);

        BARRIER();   // every wave has register-consumed buf(t&1)
        if (t + 2 < 16) STAGE(t + 2);
        if (t < 14)       { asm volatile("s_waitcnt vmcnt(8)"); }
        else if (t == 14) { asm volatile("s_waitcnt vmcnt(0)"); }
        BARRIER();
    }

    bf16* Cs = lds;
#pragma unroll
    for (int ni = 0; ni < 4; ++ni) {
        const int nl = wn * 64 + ni * 16 + l16;
        float bcol = brow ? 0.0f : bias[n0 + nl];
#pragma unroll
        for (int mi = 0; mi < 4; ++mi)
#pragma unroll
            for (int i = 0; i < 4; ++i) {
                const int ml = wm * 64 + mi * 16 + quad * 4 + i;
                float v = (acc[mi][ni][i] + (brow ? bias[m0 + ml] : bcol)) * sc;
                Cs[ml * 132 + nl] = __float2bfloat16(v);
            }
    }
    __syncthreads();
#pragma unroll
    for (int j = 0; j < 8; ++j) {
        int slot = j * 256 + tid;
        int rr = slot >> 4, cc = slot & 15;
        short8 v = *(const short8*)(Cs + rr * 132 + cc * 8);
        *(short8*)(C + (size_t)(m0 + rr) * N + n0 + cc * 8) = v;
    }
#undef STAGE
}

// ---------------------------------------------------------------------------
// O-projection GEMM (round-6 structure, measured OK).
// ---------------------------------------------------------------------------
__global__ __launch_bounds__(256, 2) void gemm_o(
    const bf16* __restrict__ A, const bf16* __restrict__ W,
    const float* __restrict__ bias, float* __restrict__ C)
{
    __shared__ bf16 lds[24576];  // 48KB

    const int lin = blockIdx.x + 16 * blockIdx.y;
    const int xcd = lin & 7;
    const int t8  = lin >> 3;
    const int m0 = (xcd * 4 + (t8 >> 4)) * 128;
    const int n0 = (((t8 & 15) + 2 * xcd) & 15) * 64;

    const int tid  = threadIdx.x;
    const int lane = tid & 63;
    const int wave = tid >> 6;
    const int quad = lane >> 4;
    const int l16  = lane & 15;
    const int wm = wave & 1;
    const int wn = wave >> 1;
    const int wbase = tid & ~63;

    const int srow = tid >> 3;
    const int scol = (tid & 7) ^ (srow & 7);
    const bf16* pA = A + (size_t)(m0 + srow) * DIM + scol * 8;
    const bf16* pB = W + (size_t)(n0 + srow) * DIM + scol * 8;

#define STAGE_O(T) do { \
    const bf16* sa_ = pA + (size_t)(T) * 64; \
    const bf16* sb_ = pB + (size_t)(T) * 64; \
    bf16* ab_ = lds + ((T) & 1) * 8192; \
    bf16* bb_ = lds + 16384 + ((T) & 1) * 4096; \
    _Pragma("unroll") for (int j = 0; j < 4; ++j) \
        async_copy16(sa_ + (size_t)(j * 32) * DIM, ab_ + (j * 256 + wbase) * 8); \
    _Pragma("unroll") for (int j = 0; j < 2; ++j) \
        async_copy16(sb_ + (size_t)(j * 32) * DIM, bb_ + (j * 256 + wbase) * 8); \
} while (0)

    f32x4 acc[4][2] = {};

    STAGE_O(0); STAGE_O(1);
    asm volatile("s_waitcnt vmcnt(6)");
    BARRIER();

#pragma unroll 2
    for (int t = 0; t < 16; ++t) {
        const bf16* As = lds + (t & 1) * 8192;
        const bf16* Bs = lds + 16384 + (t & 1) * 4096;

        short8 a2[2][4], b2[2][2];
#pragma unroll
        for (int kk = 0; kk < 2; ++kk) {
#pragma unroll
            for (int mi = 0; mi < 4; ++mi) {
                int r = wm * 64 + mi * 16 + l16;
                int p = (kk * 4 + quad) ^ (r & 7);
                a2[kk][mi] = *(const short8*)(As + r * 64 + p * 8);
            }
#pragma unroll
            for (int ni = 0; ni < 2; ++ni) {
                int r = wn * 32 + ni * 16 + l16;
                int p = (kk * 4 + quad) ^ (r & 7);
                b2[kk][ni] = *(const short8*)(Bs + r * 64 + p * 8);
            }
        }
        __builtin_amdgcn_s_setprio(1);
#pragma unroll
        for (int kk = 0; kk < 2; ++kk)
#pragma unroll
            for (int mi = 0; mi < 4; ++mi)
#pragma unroll
                for (int ni = 0; ni < 2; ++ni)
                    acc[mi][ni] = __builtin_amdgcn_mfma_f32_16x16x32_bf16(
                        a2[kk][mi], b2[kk][ni], acc[mi][ni], 0, 0, 0);
        __builtin_amdgcn_s_setprio(0);

        BARRIER();
        if (t + 2 < 16) STAGE_O(t + 2);
        if (t < 14)       { asm volatile("s_waitcnt vmcnt(6)"); }
        else if (t == 14) { asm volatile("s_waitcnt vmcnt(0)"); }
        BARRIER();
    }

    float* Cs = (float*)lds;
#pragma unroll
    for (int ni = 0; ni < 2; ++ni) {
        const int nl = wn * 32 + ni * 16 + l16;
        const float bcol = bias[n0 + nl];
#pragma unroll
        for (int mi = 0; mi < 4; ++mi)
#pragma unroll
            for (int i = 0; i < 4; ++i) {
                const int ml = wm * 64 + mi * 16 + quad * 4 + i;
                Cs[ml * 66 + nl] = acc[mi][ni][i] + bcol;
            }
    }
    __syncthreads();
#pragma unroll
    for (int j = 0; j < 8; ++j) {
        int slot = j * 256 + tid;
        int rr = slot >> 4, cc = slot & 15;
        float4 v = *(const float4*)(Cs + rr * 66 + cc * 4);
        *(float4*)(C + (size_t)(m0 + rr) * DIM + n0 + cc * 4) = v;
    }
#undef STAGE_O
}

// ---------------------------------------------------------------------------
// MFMA flash attention — 40KB LDS -> 4 blocks/CU (was 50.7KB / 3). The
// round-7 counters showed ~40% no-issue cycles at 3 waves/SIMD; occupancy
// is the filler. Changes: (1) K back to DOUBLE buffer — valid because
// QK-next reads chunk it+1 during iter it (one iter EARLY), so slot it&1's
// last reader finished at iter it-1; K-stage(it+2) issues at the TOP of
// iter it for a full-iteration latency window (extra barrier after the
// pre-loop QK protects iter-0's overwrite). (2) Pt: stride-72 pad ->
// stride-64 + 16B-granule XOR swizzle (byte ^= (l16&7)<<4, same involution
// on write and read; row stride 128B = bank wrap so the XOR alone spreads
// banks; r/r+8 2-way = free). (3) ls[] removed — epilogue 1/l via shfl.
// vmcnt ledger (simulated, 16 iters): prologue vmcnt(2); steady vmcnt(2)
// at iter end (completes V(it+1),K(it+2), leaves V(it+2)); vmcnt(0)@it=14.
// ---------------------------------------------------------------------------
__global__ __launch_bounds__(256, 4) void attn_kernel(
    const bf16* Qg, const bf16* __restrict__ Kg, const bf16* __restrict__ Vtg,
    const unsigned long long* __restrict__ Mbits, bf16* Og)
{
    __shared__ bf16 Ks[2 * 64 * 64];    // [slot c&1][f][d], 8-group XOR swizzle
    __shared__ bf16 Vts[2 * 64 * 64];   // [slot c&1][d][f], 8-group XOR swizzle
    __shared__ bf16 Pt[64 * 64];        // [t][f], 16B-granule XOR swizzle
    // total 40960B exactly -> 4 blocks/CU

    const int tid  = threadIdx.x;
    const int lane = tid & 63;
    const int wave = tid >> 6;
    const int quad = lane >> 4;
    const int l16  = lane & 15;

    const int lin = blockIdx.x + 16 * (blockIdx.y + 16 * blockIdx.z);
    const int xcd = lin & 7;
    const int t   = lin >> 3;
    const int bh  = xcd * 8 + (t >> 4);
    const int b   = bh >> 4;
    const int h   = bh & 15;
    const int t0  = (t & 15) * 64;

    const size_t qrow0 = (size_t)b * TT + t0;
    const size_t krow0 = (size_t)b * FF;
    const int wbase = tid & ~63;
    const int myrow = wave * 16 + l16;   // this lane's t-row
    const int pswz  = (l16 & 7) << 4;    // Pt byte-XOR (16B granules)
    char* ptb = (char*)Pt + myrow * 128;

    // Q fragments (B-operand: n=t=l16, k=d) direct from global
    const bf16* qptr = Qg + (qrow0 + myrow) * DIM + h * HD;
    short8 qb0 = *(const short8*)(qptr + quad * 8);
    short8 qb1 = *(const short8*)(qptr + 32 + quad * 8);

    // staging base pointers: thread covers row (tid>>3), swizzled 8-col group
    const int srow = tid >> 3;
    const int sg   = ((tid & 7) ^ (srow & 7)) * 8;
    const bf16* kS = Kg + (krow0 + srow) * DIM + h * HD + sg;
    const bf16* vS = Vtg + (size_t)(h * HD + srow) * MROWS + b * FF + sg;

#define STAGE_K(SLOT, IT) do { \
    const bf16* ks_ = kS + (size_t)((IT) * 64) * DIM; \
    bf16* kd_ = Ks + (SLOT) * 4096 + wbase * 8; \
    async_copy16(ks_, kd_); \
    async_copy16(ks_ + (size_t)32 * DIM, kd_ + 2048); \
} while (0)

#define STAGE_V(SLOT, IT) do { \
    const bf16* vs_ = vS + (IT) * 64; \
    bf16* vd_ = Vts + (SLOT) * 4096 + wbase * 8; \
    async_copy16(vs_, vd_); \
    async_copy16(vs_ + (size_t)32 * MROWS, vd_ + 2048); \
} while (0)

#define QK_CLUSTER(DST, KPTR) do { \
    _Pragma("unroll") for (int ft = 0; ft < 4; ++ft) { \
        int r_ = ft * 16 + l16; \
        short8 ka0 = *(const short8*)((KPTR) + r_ * 64 + ((quad       ^ (r_ & 7)) * 8)); \
        short8 ka1 = *(const short8*)((KPTR) + r_ * 64 + (((quad + 4) ^ (r_ & 7)) * 8)); \
        f32x4 s_ = {}; \
        s_ = __builtin_amdgcn_mfma_f32_16x16x32_bf16(ka0, qb0, s_, 0, 0, 0); \
        s_ = __builtin_amdgcn_mfma_f32_16x16x32_bf16(ka1, qb1, s_, 0, 0, 0); \
        (DST)[ft] = s_; \
    } \
} while (0)

    // mask: this lane's row, 1 word per iteration, software prefetch
    const unsigned long long* mrow = Mbits + (qrow0 + myrow) * FB;
    unsigned long long w = mrow[0];

    float lsum = 0.f;
    f32x4 oacc[4] = {};

    // prologue: K0,K1,V0 must land; V1 stays in flight (2 loads)
    STAGE_K(0, 0); STAGE_K(1, 1); STAGE_V(0, 0); STAGE_V(1, 1);
    asm volatile("s_waitcnt vmcnt(2)");
    BARRIER();

    // initial QK for chunk 0
    f32x4 scur[4];
    QK_CLUSTER(scur, Ks);
    BARRIER();   // all waves done reading K slot 0 -> iter-0 top overwrite safe

#pragma unroll 2
    for (int it = 0; it < 16; ++it) {
        // stage K(it+2) into slot it&1 at iteration TOP: its readers (QK-next
        // for chunk it, during iter it-1) passed the end-of-(it-1) barrier;
        // the load gets this whole iteration to land before vmcnt at the end.
        if (it + 2 < 16) STAGE_K((it + 2) & 1, it + 2);

        const bf16* Vc = Vts + (it & 1) * 4096;

        // prefetch next iteration's mask word
        unsigned long long nw = (it < 15) ? mrow[it + 1] : 0;

        // QK^T for chunk it+1 (matrix pipe), before softmax (VALU overlap)
        f32x4 snxt[4] = {};
        if (it < 15) QK_CLUSTER(snxt, Ks + ((it + 1) & 1) * 4096);

        // softmax on scur: exp + mask + vectorized swizzled P writes
#pragma unroll
        for (int ft = 0; ft < 4; ++ft) {
            const unsigned bits4 =
                (unsigned)(w >> (ft * 16 + quad * 4)) & 0xFu;
            union { short4v v; short s[4]; } pk;
            float psum = 0.f;
#pragma unroll
            for (int i = 0; i < 4; ++i) {
                float p = (bits4 >> i) & 1u ? __expf(scur[ft][i]) : 0.f;
                psum += p;
                pk.s[i] = (short)__bfloat16_as_ushort(__float2bfloat16(p));
            }
            lsum += psum;
            *(short4v*)(ptb + ((ft * 32 + quad * 8) ^ pswz)) = pk.v;
        }
        w = nw;

        // PV A-frags from own Pt row (in-order same-wave LDS, swizzled)
        short8 pa[2];
        pa[0] = *(const short8*)(ptb + ((quad * 16) ^ pswz));
        pa[1] = *(const short8*)(ptb + ((64 + quad * 16) ^ pswz));
        __builtin_amdgcn_s_setprio(1);
#pragma unroll
        for (int nt = 0; nt < 4; ++nt) {
            int rd = nt * 16 + l16;
#pragma unroll
            for (int kf = 0; kf < 2; ++kf) {
                int g = (kf * 4 + quad) ^ (rd & 7);
                short8 vb = *(const short8*)(Vc + rd * 64 + g * 8);
                oacc[nt] = __builtin_amdgcn_mfma_f32_16x16x32_bf16(pa[kf], vb, oacc[nt], 0, 0, 0);
            }
        }
        __builtin_amdgcn_s_setprio(0);

        BARRIER();   // all waves done reading K(it+1), V(it)
        if (it + 2 < 16) STAGE_V((it + 2) & 1, it + 2);   // slot it&1: readers just done
        if (it < 14)       { asm volatile("s_waitcnt vmcnt(2)"); }
        else if (it == 14) { asm volatile("s_waitcnt vmcnt(0)"); }
        BARRIER();   // completed stages visible to all waves

        scur[0] = snxt[0]; scur[1] = snxt[1];
        scur[2] = snxt[2]; scur[3] = snxt[3];
    }
#undef STAGE_K
#undef STAGE_V
#undef QK_CLUSTER

    // reduce l across quads (lanes sharing l16)
    lsum += __shfl_xor(lsum, 16);
    lsum += __shfl_xor(lsum, 32);

    // epilogue: normalize (l for row quad*4+i via shfl) + coalesced store
#pragma unroll
    for (int i = 0; i < 4; ++i) {
        float inv = 1.0f / __shfl(lsum, quad * 4 + i);
        const int prow = wave * 16 + quad * 4 + i;
#pragma unroll
        for (int nt = 0; nt < 4; ++nt)
            Pt[prow * 64 + nt * 16 + l16] = __float2bfloat16(oacc[nt][i] * inv);
    }
    __syncthreads();
#pragma unroll
    for (int j = 0; j < 2; ++j) {
        int s = j * 256 + tid;
        int rr = s >> 3, off = (s & 7) * 8;
        short8 v = *(const short8*)(Pt + rr * 64 + off);
        *(short8*)(Og + (qrow0 + rr) * DIM + h * HD + off) = v;
    }
}

// ---------------------------------------------------------------------------
extern "C" void kernel_launch(void* const* d_in, const int* in_sizes, int n_in,
                              void* d_out, int out_size, void* d_ws, size_t ws_size,
                              hipStream_t stream) {
    const float* X_to   = (const float*)d_in[0];
    const float* X_from = (const float*)d_in[1];
    const int*   mask   = (const int*)  d_in[2];
    const float* Wq     = (const float*)d_in[3];
    const float* bq     = (const float*)d_in[4];
    const float* Wk     = (const float*)d_in[5];
    const float* bk     = (const float*)d_in[6];
    const float* Wv     = (const float*)d_in[7];
    const float* bv     = (const float*)d_in[8];
    const float* Wo     = (const float*)d_in[9];
    const float* bo     = (const float*)d_in[10];
    float* out = (float*)d_out;

    char* ws = (char*)d_ws;
    bf16* Xt16 = (bf16*)(ws);
    bf16* Xf16 = (bf16*)(ws + (8u  << 20));
    bf16* Wq16 = (bf16*)(ws + (16u << 20));
    bf16* Wv16 = (bf16*)(ws + (18u << 20));
    bf16* Wk16 = (bf16*)(ws + (20u << 20));
    bf16* Wo16 = (bf16*)(ws + (22u << 20));
    bf16* Q16  = (bf16*)(ws + (24u << 20));
    bf16* K16  = (bf16*)(ws + (32u << 20));
    bf16* Vt16 = (bf16*)(ws + (40u << 20));
    unsigned long long* Mb = (unsigned long long*)(ws + (48u << 20));

    ConvArgs ca;
    ca.src[0] = X_to;   ca.dst[0] = Xt16; ca.nvec[0] = MROWS * DIM / 4;
    ca.src[1] = X_from; ca.dst[1] = Xf16; ca.nvec[1] = MROWS * DIM / 4;
    ca.src[2] = Wq;     ca.dst[2] = Wq16; ca.nvec[2] = DIM * DIM / 4;
    ca.src[3] = Wv;     ca.dst[3] = Wv16; ca.nvec[3] = DIM * DIM / 4;
    ca.src[4] = Wk;     ca.dst[4] = Wk16; ca.nvec[4] = DIM * DIM / 4;
    ca.src[5] = Wo;     ca.dst[5] = Wo16; ca.nvec[5] = DIM * DIM / 4;
    int cum = 0;
    for (int k = 0; k < 6; ++k) { cum += ca.nvec[k] / 256; ca.blk_end[k] = cum; }
    ca.mask = mask; ca.Mb = Mb;
    convert_pack<<<cum + 1024, 256, 0, stream>>>(ca);

    QkvArgs qa;
    qa.A[0] = Xt16; qa.W[0] = Wq16; qa.bias[0] = bq; qa.C[0] = Q16;
    qa.N[0] = DIM; qa.biasRow[0] = 0; qa.scale[0] = 0.125f;
    qa.A[1] = Xf16; qa.W[1] = Wv16; qa.bias[1] = bv; qa.C[1] = K16;
    qa.N[1] = DIM; qa.biasRow[1] = 0; qa.scale[1] = 1.0f;
    qa.A[2] = Wk16; qa.W[2] = Xf16; qa.bias[2] = bk; qa.C[2] = Vt16;
    qa.N[2] = MROWS; qa.biasRow[2] = 1; qa.scale[2] = 1.0f;
    gemm_qkv<<<dim3(8, 32, 3), 256, 0, stream>>>(qa);

    attn_kernel<<<dim3(TT / 64, NH, BB), 256, 0, stream>>>(
        Q16, K16, Vt16, Mb, Q16);

    gemm_o<<<dim3(DIM / 64, MROWS / 128), 256, 0, stream>>>(Q16, Wo16, bo, out);
}